// Round 11
// baseline (6732.043 us; speedup 1.0000x reference)
//
#include <hip/hip_runtime.h>
#include <math.h>

#define TT   1024
#define DM   768
#define NH   12
#define HD   64
#define FFD  2048
#define NE   8
#define SQ   512
#define NB   2
#define NL   4
#define NV   32000
#define REPS 1e-6f
#define LMC  3200

typedef int   int4v __attribute__((ext_vector_type(4)));
typedef float f32x4 __attribute__((ext_vector_type(4)));
typedef short s16x8 __attribute__((ext_vector_type(8)));

__device__ __forceinline__ float b2f(ushort u) {
  return __uint_as_float(((unsigned)u) << 16);
}
__device__ __forceinline__ ushort f2b(float f) {
  unsigned i = __float_as_uint(f);
  return (ushort)((i + 0x7FFFu + ((i >> 16) & 1u)) >> 16);
}

// ================= verified fp32 pieces =================
__global__ __launch_bounds__(256) void k_embed(const int* __restrict__ ids,
    const float* __restrict__ tok, const float* __restrict__ pos, float* __restrict__ x) {
  int t = blockIdx.x; int s = t % SQ; int id = ids[t];
  for (int d = threadIdx.x; d < DM; d += 256)
    x[t * DM + d] = tok[(size_t)id * DM + d] + pos[s * DM + d];
}

__global__ __launch_bounds__(64) void k_router(const float* __restrict__ xn,
    const float* __restrict__ rw, int* __restrict__ topi, float* __restrict__ topw,
    int* __restrict__ posb, int* __restrict__ slot, int* __restrict__ counts) {
  int t = blockIdx.x, l = threadIdx.x;
  float acc[NE] = {};
  for (int d = l; d < DM; d += 64) {
    float xv = xn[t * DM + d];
    const float* r = &rw[d * NE];
#pragma unroll
    for (int e = 0; e < NE; ++e) acc[e] += xv * r[e];
  }
#pragma unroll
  for (int off = 32; off > 0; off >>= 1)
#pragma unroll
    for (int e = 0; e < NE; ++e) acc[e] += __shfl_down(acc[e], off, 64);
  if (l == 0) {
    float mx = acc[0];
#pragma unroll
    for (int e = 1; e < NE; ++e) mx = fmaxf(mx, acc[e]);
    float p[NE], sum = 0.f;
#pragma unroll
    for (int e = 0; e < NE; ++e) { p[e] = expf(acc[e] - mx); sum += p[e]; }
#pragma unroll
    for (int e = 0; e < NE; ++e) p[e] /= sum;
    int i0 = 0;
    for (int e = 1; e < NE; ++e) if (p[e] > p[i0]) i0 = e;
    int i1 = (i0 == 0) ? 1 : 0;
    for (int e = 0; e < NE; ++e) if (e != i0 && p[e] > p[i1]) i1 = e;
    float w0 = p[i0], w1 = p[i1], inv = 1.f / (w0 + w1);
    w0 *= inv; w1 *= inv;
    int p0 = atomicAdd(&counts[i0], 1);
    int p1 = atomicAdd(&counts[i1], 1);
    topi[2 * t] = i0; topi[2 * t + 1] = i1;
    topw[2 * t] = w0; topw[2 * t + 1] = w1;
    posb[2 * t] = p0; posb[2 * t + 1] = p1;
    slot[i0 * TT + p0] = t; slot[i1 * TT + p1] = t;
  }
}

__global__ void k_zero8(int* c) { if (threadIdx.x < NE) c[threadIdx.x] = 0; }

__global__ void k_offsets(const int* __restrict__ counts, int* __restrict__ off) {
  int a = 0;
  for (int e = 0; e < NE; ++e) { off[e] = a; a += counts[e]; }
  off[NE] = a;
}

__global__ __launch_bounds__(256) void k_combine(const float* __restrict__ eo,
    const int* __restrict__ topi, const float* __restrict__ topw,
    const int* __restrict__ posb, const int* __restrict__ offs, float* __restrict__ x) {
  int t = blockIdx.x;
  int r0 = offs[topi[2 * t]] + posb[2 * t];
  int r1 = offs[topi[2 * t + 1]] + posb[2 * t + 1];
  float w0 = topw[2 * t], w1 = topw[2 * t + 1];
  for (int d = threadIdx.x; d < DM; d += 256)
    x[t * DM + d] += w0 * eo[(size_t)r0 * DM + d] + w1 * eo[(size_t)r1 * DM + d];
}

// fp32 attention reading fused fp32 qkv[t][2304] (r1 k_attn, base-addr change only)
__global__ __launch_bounds__(256) void k_attn_qkv(const float* __restrict__ qkv,
    float* __restrict__ O) {
  __shared__ float qrow[HD];
  __shared__ float sc[SQ];
  __shared__ float red[256];
  __shared__ float pv[4][HD];
  int idx = blockIdx.x;
  int s = idx % SQ; int h = (idx / SQ) % NH; int b = idx / (SQ * NH);
  int tid = threadIdx.x;
  if (tid < HD) qrow[tid] = qkv[(size_t)(b * SQ + s) * (3 * DM) + h * HD + tid];
  __syncthreads();
  for (int kk = tid; kk < SQ; kk += 256) {
    const float4* kp = (const float4*)&qkv[(size_t)(b * SQ + kk) * (3 * DM) + DM + h * HD];
    float dot = 0.f;
#pragma unroll
    for (int i = 0; i < HD / 4; ++i) {
      float4 kv = kp[i];
      dot += kv.x * qrow[4 * i] + kv.y * qrow[4 * i + 1]
           + kv.z * qrow[4 * i + 2] + kv.w * qrow[4 * i + 3];
    }
    sc[kk] = dot * 0.125f;
  }
  __syncthreads();
  float m = fmaxf(sc[tid], sc[tid + 256]);
  red[tid] = m; __syncthreads();
  for (int r = 128; r > 0; r >>= 1) { if (tid < r) red[tid] = fmaxf(red[tid], red[tid + r]); __syncthreads(); }
  m = red[0]; __syncthreads();
  float e0 = expf(sc[tid] - m), e1 = expf(sc[tid + 256] - m);
  sc[tid] = e0; sc[tid + 256] = e1;
  red[tid] = e0 + e1; __syncthreads();
  for (int r = 128; r > 0; r >>= 1) { if (tid < r) red[tid] += red[tid + r]; __syncthreads(); }
  float inv = 1.0f / red[0];
  __syncthreads();
  int g = tid >> 6, d = tid & 63;
  float accv = 0.f;
  for (int kk = g; kk < SQ; kk += 4)
    accv += sc[kk] * qkv[(size_t)(b * SQ + kk) * (3 * DM) + 2 * DM + h * HD + d];
  pv[g][d] = accv; __syncthreads();
  if (g == 0)
    O[(size_t)(b * SQ + s) * DM + h * HD + d] = (pv[0][d] + pv[1][d] + pv[2][d] + pv[3][d]) * inv;
}

// ================= split-precision helpers =================
// rmsnorm: fp32 out + hi/lo bf16 planes
__global__ __launch_bounds__(256) void k_rmsnorm_sb(const float* __restrict__ x,
    const float* __restrict__ w, float* __restrict__ y,
    ushort* __restrict__ yh, ushort* __restrict__ yl) {
  __shared__ float red[256];
  int t = blockIdx.x, tid = threadIdx.x;
  float ss = 0.f;
  for (int d = tid; d < DM; d += 256) { float v = x[t * DM + d]; ss += v * v; }
  red[tid] = ss; __syncthreads();
  for (int s = 128; s > 0; s >>= 1) { if (tid < s) red[tid] += red[tid + s]; __syncthreads(); }
  float inv = 1.0f / sqrtf(red[0] / (float)DM + REPS);
  for (int d = tid; d < DM; d += 256) {
    float v = w[d] * x[t * DM + d] * inv;
    ushort h = f2b(v);
    y[t * DM + d] = v;
    yh[t * DM + d] = h;
    yl[t * DM + d] = f2b(v - b2f(h));
  }
}

// fp32 [t][DM] -> hi/lo planes
__global__ __launch_bounds__(256) void k_split(const float* __restrict__ in,
    ushort* __restrict__ oh, ushort* __restrict__ ol) {
  int t = blockIdx.x;
  for (int d = threadIdx.x; d < DM; d += 256) {
    float v = in[(size_t)t * DM + d];
    ushort h = f2b(v);
    oh[(size_t)t * DM + d] = h;
    ol[(size_t)t * DM + d] = f2b(v - b2f(h));
  }
}

// transpose+convert split: fp32 in[K][N(stride ns)] -> hi/lo bf16 out[rowmap(n)][K]
__global__ __launch_bounds__(256) void k_tconv_s(const float* __restrict__ in,
    ushort* __restrict__ outh, ushort* __restrict__ outl, int K, int ns, int mode) {
  __shared__ float tile[32][33];
  int n0 = blockIdx.x * 32, k0 = blockIdx.y * 32;
  int c = threadIdx.x & 31, rq = threadIdx.x >> 5;
#pragma unroll
  for (int rr = rq; rr < 32; rr += 8)
    tile[rr][c] = in[(size_t)(k0 + rr) * ns + n0 + c];
  __syncthreads();
#pragma unroll
  for (int rr = rq; rr < 32; rr += 8) {
    int n = n0 + rr;
    int orow = (mode == 0) ? n : (((n >> 4) << 5) + ((mode == 1) ? 0 : 16) + (n & 15));
    float v = tile[c][rr];
    ushort h = f2b(v);
    outh[(size_t)orow * K + k0 + c] = h;
    outl[(size_t)orow * K + k0 + c] = f2b(v - b2f(h));
  }
}

// plain bf16 pieces for the verified LM-head path
__global__ __launch_bounds__(256) void k_rmsnorm_b(const float* __restrict__ x,
    const float* __restrict__ w, ushort* __restrict__ y) {
  __shared__ float red[256];
  int t = blockIdx.x, tid = threadIdx.x;
  float ss = 0.f;
  for (int d = tid; d < DM; d += 256) { float v = x[t * DM + d]; ss += v * v; }
  red[tid] = ss; __syncthreads();
  for (int s = 128; s > 0; s >>= 1) { if (tid < s) red[tid] += red[tid + s]; __syncthreads(); }
  float inv = 1.0f / sqrtf(red[0] / (float)DM + REPS);
  for (int d = tid; d < DM; d += 256)
    y[t * DM + d] = f2b(w[d] * x[t * DM + d] * inv);
}

__global__ __launch_bounds__(256) void k_tconv(const float* __restrict__ in,
    ushort* __restrict__ out, int K, int ns, int mode) {
  __shared__ float tile[32][33];
  int n0 = blockIdx.x * 32, k0 = blockIdx.y * 32;
  int c = threadIdx.x & 31, rq = threadIdx.x >> 5;
#pragma unroll
  for (int rr = rq; rr < 32; rr += 8)
    tile[rr][c] = in[(size_t)(k0 + rr) * ns + n0 + c];
  __syncthreads();
#pragma unroll
  for (int rr = rq; rr < 32; rr += 8) {
    int n = n0 + rr;
    int orow = (mode == 0) ? n : (((n >> 4) << 5) + ((mode == 1) ? 0 : 16) + (n & 15));
    out[(size_t)orow * K + k0 + c] = f2b(tile[c][rr]);
  }
}

// ================= GEMMs =================
#define EPI_BF16 0
#define EPI_RES  1
#define EPI_F32  2
#define EPI_GU   3
#define EPI_DOWN 4

// ---- r5-verified single-precision bf16 GEMM (LM head only) ----
template<int EPI, int RM>
__global__ __launch_bounds__(256) void k_gmm(
    const ushort* __restrict__ A, const ushort* __restrict__ Bt,
    ushort* __restrict__ Cb, float* __restrict__ Cf,
    int M, int K, int ldc, int e_arg,
    const int* __restrict__ slot, const int* __restrict__ counts,
    const int* __restrict__ offs) {
  (void)e_arg; (void)slot; (void)counts; (void)offs; (void)Cb;
  int cnt = M;
  int m0 = blockIdx.y * 128;
  if (m0 >= cnt) return;
  int n0 = blockIdx.x * 128;
  __shared__ __align__(16) ushort As[128 * 40];
  __shared__ __align__(16) ushort Bs[128 * 40];
  int tid = threadIdx.x;
  int lane = tid & 63;
  int wave = tid >> 6;
  int wr = wave >> 1, wc = wave & 1;
  int ar1 = tid >> 2, ar2 = ar1 + 64, kc = tid & 3;
  const ushort* Arow1 = A + (size_t)(m0 + ar1) * K;
  const ushort* Arow2 = A + (size_t)(m0 + ar2) * K;
  const ushort* Brow1 = Bt + (size_t)(n0 + ar1) * K;
  const ushort* Brow2 = Bt + (size_t)(n0 + ar2) * K;
  f32x4 zr = {0.f, 0.f, 0.f, 0.f};
  f32x4 acc[4][4];
#pragma unroll
  for (int i = 0; i < 4; ++i)
#pragma unroll
    for (int j = 0; j < 4; ++j) acc[i][j] = zr;
  int rl = lane & 15, g = lane >> 4;
  for (int k0 = 0; k0 < K; k0 += 32) {
    s16x8 va1 = *(const s16x8*)(Arow1 + k0 + kc * 8);
    s16x8 va2 = *(const s16x8*)(Arow2 + k0 + kc * 8);
    s16x8 vb1 = *(const s16x8*)(Brow1 + k0 + kc * 8);
    s16x8 vb2 = *(const s16x8*)(Brow2 + k0 + kc * 8);
    __syncthreads();
    *(s16x8*)&As[ar1 * 40 + kc * 8] = va1;
    *(s16x8*)&As[ar2 * 40 + kc * 8] = va2;
    *(s16x8*)&Bs[ar1 * 40 + kc * 8] = vb1;
    *(s16x8*)&Bs[ar2 * 40 + kc * 8] = vb2;
    __syncthreads();
    s16x8 av[4], bv[4];
#pragma unroll
    for (int mi = 0; mi < 4; ++mi)
      av[mi] = *(const s16x8*)&As[(wr * 64 + mi * 16 + rl) * 40 + g * 8];
#pragma unroll
    for (int ni = 0; ni < 4; ++ni)
      bv[ni] = *(const s16x8*)&Bs[(wc * 64 + ni * 16 + rl) * 40 + g * 8];
#pragma unroll
    for (int mi = 0; mi < 4; ++mi)
#pragma unroll
      for (int ni = 0; ni < 4; ++ni)
        acc[mi][ni] = __builtin_amdgcn_mfma_f32_16x16x32_bf16(av[mi], bv[ni], acc[mi][ni], 0, 0, 0);
  }
  int rg4 = (lane >> 4) * 4;
#pragma unroll
  for (int mi = 0; mi < 4; ++mi)
#pragma unroll
    for (int rg = 0; rg < 4; ++rg) {
      int rloc = m0 + wr * 64 + mi * 16 + rg4 + rg;
#pragma unroll
      for (int ni = 0; ni < 4; ++ni)
        Cf[(size_t)rloc * ldc + n0 + wc * 64 + ni * 16 + rl] = acc[mi][ni][rg];
    }
}

// ---- split-precision (bf16 hi+lo, 3-pass) GEMM: C = A @ Bt^T, ~fp32 accuracy ----
template<int EPI, int RM>
__global__ __launch_bounds__(256) void k_gmm_s(
    const ushort* __restrict__ Ah, const ushort* __restrict__ Al,
    const ushort* __restrict__ Bh, const ushort* __restrict__ Bl,
    ushort* __restrict__ Ch, ushort* __restrict__ Cl, float* __restrict__ Cf,
    int M, int K, int ldc, int e,
    const int* __restrict__ slot, const int* __restrict__ counts,
    const int* __restrict__ offs) {
  int cnt = (RM == 0) ? M : counts[e];
  int m0 = blockIdx.y * 128;
  if (m0 >= cnt) return;
  int n0 = blockIdx.x * 128;
  int off = (RM == 0) ? 0 : offs[e];

  __shared__ __align__(16) ushort Ahs[128 * 40];
  __shared__ __align__(16) ushort Als[128 * 40];
  __shared__ __align__(16) ushort Bhs[128 * 40];
  __shared__ __align__(16) ushort Bls[128 * 40];

  int tid = threadIdx.x;
  int wave = tid >> 6, lane = tid & 63;
  int wr = wave >> 1, wc = wave & 1;

  int ar1 = tid >> 2, ar2 = ar1 + 64, kc = tid & 3;
  size_t aoff1, aoff2;
  if (RM == 0) {
    aoff1 = (size_t)(m0 + ar1) * K;
    aoff2 = (size_t)(m0 + ar2) * K;
  } else if (RM == 1) {
    aoff1 = (size_t)slot[e * TT + min(m0 + ar1, cnt - 1)] * K;
    aoff2 = (size_t)slot[e * TT + min(m0 + ar2, cnt - 1)] * K;
  } else {
    aoff1 = (size_t)(off + min(m0 + ar1, cnt - 1)) * K;
    aoff2 = (size_t)(off + min(m0 + ar2, cnt - 1)) * K;
  }
  size_t boff1 = (size_t)(n0 + ar1) * K;
  size_t boff2 = (size_t)(n0 + ar2) * K;

  f32x4 zr = {0.f, 0.f, 0.f, 0.f};
  f32x4 acc[4][4];
#pragma unroll
  for (int i = 0; i < 4; ++i)
#pragma unroll
    for (int j = 0; j < 4; ++j) acc[i][j] = zr;

  int rl = lane & 15, g = lane >> 4;
  for (int k0 = 0; k0 < K; k0 += 32) {
    s16x8 vah1 = *(const s16x8*)(Ah + aoff1 + k0 + kc * 8);
    s16x8 vah2 = *(const s16x8*)(Ah + aoff2 + k0 + kc * 8);
    s16x8 val1 = *(const s16x8*)(Al + aoff1 + k0 + kc * 8);
    s16x8 val2 = *(const s16x8*)(Al + aoff2 + k0 + kc * 8);
    s16x8 vbh1 = *(const s16x8*)(Bh + boff1 + k0 + kc * 8);
    s16x8 vbh2 = *(const s16x8*)(Bh + boff2 + k0 + kc * 8);
    s16x8 vbl1 = *(const s16x8*)(Bl + boff1 + k0 + kc * 8);
    s16x8 vbl2 = *(const s16x8*)(Bl + boff2 + k0 + kc * 8);
    __syncthreads();
    *(s16x8*)&Ahs[ar1 * 40 + kc * 8] = vah1;
    *(s16x8*)&Ahs[ar2 * 40 + kc * 8] = vah2;
    *(s16x8*)&Als[ar1 * 40 + kc * 8] = val1;
    *(s16x8*)&Als[ar2 * 40 + kc * 8] = val2;
    *(s16x8*)&Bhs[ar1 * 40 + kc * 8] = vbh1;
    *(s16x8*)&Bhs[ar2 * 40 + kc * 8] = vbh2;
    *(s16x8*)&Bls[ar1 * 40 + kc * 8] = vbl1;
    *(s16x8*)&Bls[ar2 * 40 + kc * 8] = vbl2;
    __syncthreads();
#pragma unroll
    for (int mi = 0; mi < 4; ++mi) {
      int ra = (wr * 64 + mi * 16 + rl) * 40 + g * 8;
      s16x8 avh = *(const s16x8*)&Ahs[ra];
      s16x8 avl = *(const s16x8*)&Als[ra];
#pragma unroll
      for (int ni = 0; ni < 4; ++ni) {
        int rb = (wc * 64 + ni * 16 + rl) * 40 + g * 8;
        s16x8 bvh = *(const s16x8*)&Bhs[rb];
        s16x8 bvl = *(const s16x8*)&Bls[rb];
        f32x4 a = acc[mi][ni];
        a = __builtin_amdgcn_mfma_f32_16x16x32_bf16(avl, bvh, a, 0, 0, 0);
        a = __builtin_amdgcn_mfma_f32_16x16x32_bf16(avh, bvl, a, 0, 0, 0);
        a = __builtin_amdgcn_mfma_f32_16x16x32_bf16(avh, bvh, a, 0, 0, 0);
        acc[mi][ni] = a;
      }
    }
  }

  int rg4 = (lane >> 4) * 4;
#pragma unroll
  for (int mi = 0; mi < 4; ++mi) {
#pragma unroll
    for (int rg = 0; rg < 4; ++rg) {
      int rloc = m0 + wr * 64 + mi * 16 + rg4 + rg;
      if ((EPI == EPI_GU || EPI == EPI_DOWN) && rloc >= cnt) continue;
      if (EPI == EPI_GU) {
#pragma unroll
        for (int ni = 0; ni < 4; ni += 2) {
          float gv = acc[mi][ni][rg], uv = acc[mi][ni + 1][rg];
          float hv = gv / (1.f + __expf(-gv)) * uv;
          int fq = (n0 + wc * 64 + ni * 16) >> 5;
          size_t ix = (size_t)(off + rloc) * ldc + fq * 16 + rl;
          ushort h = f2b(hv);
          Ch[ix] = h;
          Cl[ix] = f2b(hv - b2f(h));
        }
      } else if (EPI == EPI_RES) {
#pragma unroll
        for (int ni = 0; ni < 4; ++ni) {
          size_t ix = (size_t)rloc * ldc + n0 + wc * 64 + ni * 16 + rl;
          Cf[ix] += acc[mi][ni][rg];
        }
      } else if (EPI == EPI_F32) {
#pragma unroll
        for (int ni = 0; ni < 4; ++ni)
          Cf[(size_t)rloc * ldc + n0 + wc * 64 + ni * 16 + rl] = acc[mi][ni][rg];
      } else {  // EPI_DOWN
#pragma unroll
        for (int ni = 0; ni < 4; ++ni)
          Cf[(size_t)(off + rloc) * ldc + n0 + wc * 64 + ni * 16 + rl] = acc[mi][ni][rg];
      }
    }
  }
}

extern "C" void kernel_launch(void* const* d_in, const int* in_sizes, int n_in,
                              void* d_out, int out_size, void* d_ws, size_t ws_size,
                              hipStream_t stream) {
  (void)in_sizes; (void)n_in; (void)out_size; (void)ws_size;
  const int*   ids = (const int*)d_in[0];
  const float* tok = (const float*)d_in[1];
  const float* pos = (const float*)d_in[2];
  const float* wq  = (const float*)d_in[3];
  const float* wk  = (const float*)d_in[4];
  const float* wv  = (const float*)d_in[5];
  const float* wo  = (const float*)d_in[6];
  const float* n1w = (const float*)d_in[7];
  const float* n2w = (const float*)d_in[8];
  const float* rw  = (const float*)d_in[9];
  const float* gw  = (const float*)d_in[10];
  const float* uw  = (const float*)d_in[11];
  const float* dw  = (const float*)d_in[12];
  const float* fnw = (const float*)d_in[13];
  const float* lmw = (const float*)d_in[14];
  float* out = (float*)d_out;

  char* p = (char*)d_ws;
  auto alloc = [&](size_t bytes) { char* r = p; p += (bytes + 255) & ~(size_t)255; return r; };
  float*  x    = (float*)alloc((size_t)TT * DM * 4);
  float*  xn   = (float*)alloc((size_t)TT * DM * 4);
  ushort* xh   = (ushort*)alloc((size_t)TT * DM * 2);
  ushort* xl   = (ushort*)alloc((size_t)TT * DM * 2);
  float*  qkv  = (float*)alloc((size_t)TT * 3 * DM * 4);
  float*  ao   = (float*)alloc((size_t)TT * DM * 4);
  ushort* aoh  = (ushort*)alloc((size_t)TT * DM * 2);
  ushort* aol  = (ushort*)alloc((size_t)TT * DM * 2);
  ushort* Hh   = (ushort*)alloc((size_t)2 * TT * FFD * 2);
  ushort* Hl   = (ushort*)alloc((size_t)2 * TT * FFD * 2);
  float*  eo   = (float*)alloc((size_t)2 * TT * DM * 4);
  float*  topw = (float*)alloc((size_t)2 * TT * 4);
  int* topi    = (int*)alloc((size_t)2 * TT * 4);
  int* posb    = (int*)alloc((size_t)2 * TT * 4);
  int* slot    = (int*)alloc((size_t)NE * TT * 4);
  int* counts  = (int*)alloc(256);
  int* offs    = (int*)alloc(256);
  ushort* wqkv_h = (ushort*)alloc((size_t)3 * DM * DM * 2);
  ushort* wqkv_l = (ushort*)alloc((size_t)3 * DM * DM * 2);
  ushort* wo_h   = (ushort*)alloc((size_t)DM * DM * 2);
  ushort* wo_l   = (ushort*)alloc((size_t)DM * DM * 2);
  ushort* we_h   = (ushort*)alloc((size_t)2 * FFD * DM * 2);  // per-expert gate+up / LM chunk
  ushort* we_l   = (ushort*)alloc((size_t)2 * FFD * DM * 2);
  ushort* wd_h   = (ushort*)alloc((size_t)FFD * DM * 2);
  ushort* wd_l   = (ushort*)alloc((size_t)FFD * DM * 2);
  ushort* xnb    = (ushort*)alloc((size_t)TT * DM * 2);
  // total ~76 MB

  k_embed<<<TT, 256, 0, stream>>>(ids, tok, pos, x);
  for (int l = 0; l < NL; ++l) {
    // attention weights -> split transposed
    k_tconv_s<<<dim3(24, 24), 256, 0, stream>>>(wq + (size_t)l * DM * DM, wqkv_h,               wqkv_l,               DM, DM, 0);
    k_tconv_s<<<dim3(24, 24), 256, 0, stream>>>(wk + (size_t)l * DM * DM, wqkv_h + DM * DM,     wqkv_l + DM * DM,     DM, DM, 0);
    k_tconv_s<<<dim3(24, 24), 256, 0, stream>>>(wv + (size_t)l * DM * DM, wqkv_h + 2 * DM * DM, wqkv_l + 2 * DM * DM, DM, DM, 0);
    k_tconv_s<<<dim3(24, 24), 256, 0, stream>>>(wo + (size_t)l * DM * DM, wo_h,                 wo_l,                 DM, DM, 0);

    // attention (split QKV GEMM -> fp32 core -> split O-proj)
    k_rmsnorm_sb<<<TT, 256, 0, stream>>>(x, n1w + l * DM, xn, xh, xl);
    k_gmm_s<EPI_F32, 0><<<dim3(18, 8), 256, 0, stream>>>(
        xh, xl, wqkv_h, wqkv_l, nullptr, nullptr, qkv, TT, DM, 3 * DM, 0, nullptr, nullptr, nullptr);
    k_attn_qkv<<<NB * NH * SQ, 256, 0, stream>>>(qkv, ao);
    k_split<<<TT, 256, 0, stream>>>(ao, aoh, aol);
    k_gmm_s<EPI_RES, 0><<<dim3(6, 8), 256, 0, stream>>>(
        aoh, aol, wo_h, wo_l, nullptr, nullptr, x, TT, DM, DM, 0, nullptr, nullptr, nullptr);

    // MoE: fp32 routing + split expert GEMMs
    k_rmsnorm_sb<<<TT, 256, 0, stream>>>(x, n2w + l * DM, xn, xh, xl);
    k_zero8<<<1, 64, 0, stream>>>(counts);
    k_router<<<TT, 64, 0, stream>>>(xn, rw + (size_t)l * DM * NE, topi, topw, posb, slot, counts);
    k_offsets<<<1, 1, 0, stream>>>(counts, offs);
    for (int e = 0; e < NE; ++e) {
      const float* gwe = gw + ((size_t)l * NE + e) * DM * FFD;
      const float* uwe = uw + ((size_t)l * NE + e) * DM * FFD;
      const float* dwe = dw + ((size_t)l * NE + e) * FFD * DM;
      k_tconv_s<<<dim3(64, 24), 256, 0, stream>>>(gwe, we_h, we_l, DM, FFD, 1);
      k_tconv_s<<<dim3(64, 24), 256, 0, stream>>>(uwe, we_h, we_l, DM, FFD, 2);
      k_tconv_s<<<dim3(24, 64), 256, 0, stream>>>(dwe, wd_h, wd_l, FFD, DM, 0);
      k_gmm_s<EPI_GU, 1><<<dim3(32, 8), 256, 0, stream>>>(
          xh, xl, we_h, we_l, Hh, Hl, nullptr, TT, DM, FFD, e, slot, counts, offs);
      k_gmm_s<EPI_DOWN, 2><<<dim3(6, 8), 256, 0, stream>>>(
          Hh, Hl, wd_h, wd_l, nullptr, nullptr, eo, TT, FFD, DM, e, slot, counts, offs);
    }
    k_combine<<<TT, 256, 0, stream>>>(eo, topi, topw, posb, offs, x);
  }

  // LM head: r5-verified pure-bf16 path (after all routing -> safe)
  k_rmsnorm_b<<<TT, 256, 0, stream>>>(x, fnw, xnb);
  for (int c = 0; c < NV / LMC; ++c) {
    k_tconv<<<dim3(LMC / 32, 24), 256, 0, stream>>>(lmw + c * LMC, we_h, DM, NV, 0);
    k_gmm<EPI_F32, 0><<<dim3(LMC / 128, 8), 256, 0, stream>>>(
        xnb, we_h, nullptr, out + c * LMC, TT, DM, NV, 0, nullptr, nullptr, nullptr);
  }
}

// Round 12
// 2043.954 us; speedup vs baseline: 3.2936x; 3.2936x over previous
//
#include <hip/hip_runtime.h>
#include <math.h>

#define TT   1024
#define DM   768
#define NH   12
#define HD   64
#define FFD  2048
#define NE   8
#define SQ   512
#define NB   2
#define NL   4
#define NV   32000
#define REPS 1e-6f
#define LMC  3200
#define QB   16

typedef float f32x4 __attribute__((ext_vector_type(4)));
typedef short s16x8 __attribute__((ext_vector_type(8)));

__device__ __forceinline__ float b2f(ushort u) {
  return __uint_as_float(((unsigned)u) << 16);
}
__device__ __forceinline__ ushort f2b(float f) {
  unsigned i = __float_as_uint(f);
  return (ushort)((i + 0x7FFFu + ((i >> 16) & 1u)) >> 16);
}

// ================= verified small kernels =================
__global__ __launch_bounds__(256) void k_embed(const int* __restrict__ ids,
    const float* __restrict__ tok, const float* __restrict__ pos, float* __restrict__ x) {
  int t = blockIdx.x; int s = t % SQ; int id = ids[t];
  for (int d = threadIdx.x; d < DM; d += 256)
    x[t * DM + d] = tok[(size_t)id * DM + d] + pos[s * DM + d];
}

__global__ __launch_bounds__(64) void k_router(const float* __restrict__ xn,
    const float* __restrict__ rw, int* __restrict__ topi, float* __restrict__ topw,
    int* __restrict__ posb, int* __restrict__ slot, int* __restrict__ counts) {
  int t = blockIdx.x, l = threadIdx.x;
  float acc[NE] = {};
  for (int d = l; d < DM; d += 64) {
    float xv = xn[t * DM + d];
    const float* r = &rw[d * NE];
#pragma unroll
    for (int e = 0; e < NE; ++e) acc[e] += xv * r[e];
  }
#pragma unroll
  for (int off = 32; off > 0; off >>= 1)
#pragma unroll
    for (int e = 0; e < NE; ++e) acc[e] += __shfl_down(acc[e], off, 64);
  if (l == 0) {
    float mx = acc[0];
#pragma unroll
    for (int e = 1; e < NE; ++e) mx = fmaxf(mx, acc[e]);
    float p[NE], sum = 0.f;
#pragma unroll
    for (int e = 0; e < NE; ++e) { p[e] = expf(acc[e] - mx); sum += p[e]; }
#pragma unroll
    for (int e = 0; e < NE; ++e) p[e] /= sum;
    int i0 = 0;
    for (int e = 1; e < NE; ++e) if (p[e] > p[i0]) i0 = e;
    int i1 = (i0 == 0) ? 1 : 0;
    for (int e = 0; e < NE; ++e) if (e != i0 && p[e] > p[i1]) i1 = e;
    float w0 = p[i0], w1 = p[i1], inv = 1.f / (w0 + w1);
    w0 *= inv; w1 *= inv;
    int p0 = atomicAdd(&counts[i0], 1);
    int p1 = atomicAdd(&counts[i1], 1);
    topi[2 * t] = i0; topi[2 * t + 1] = i1;
    topw[2 * t] = w0; topw[2 * t + 1] = w1;
    posb[2 * t] = p0; posb[2 * t + 1] = p1;
    slot[i0 * TT + p0] = t; slot[i1 * TT + p1] = t;
  }
}

__global__ void k_zero8(int* c) { if (threadIdx.x < NE) c[threadIdx.x] = 0; }

__global__ void k_offsets(const int* __restrict__ counts, int* __restrict__ off) {
  int a = 0;
  for (int e = 0; e < NE; ++e) { off[e] = a; a += counts[e]; }
  off[NE] = a;
}

__global__ __launch_bounds__(256) void k_combine(const float* __restrict__ eo,
    const int* __restrict__ topi, const float* __restrict__ topw,
    const int* __restrict__ posb, const int* __restrict__ offs, float* __restrict__ x) {
  int t = blockIdx.x;
  int r0 = offs[topi[2 * t]] + posb[2 * t];
  int r1 = offs[topi[2 * t + 1]] + posb[2 * t + 1];
  float w0 = topw[2 * t], w1 = topw[2 * t + 1];
  for (int d = threadIdx.x; d < DM; d += 256)
    x[t * DM + d] += w0 * eo[(size_t)r0 * DM + d] + w1 * eo[(size_t)r1 * DM + d];
}

// ================= tiled fp32 attention: 16 q-rows per block =================
__global__ __launch_bounds__(256) void k_attn2(const float* __restrict__ qkv,
    float* __restrict__ O) {
  __shared__ float Qs[QB][64];
  __shared__ float KVs[128][68];    // padded: stride 272B (16B aligned), breaks bank aliasing
  __shared__ float sc[QB][516];     // padded for softmax access pattern
  __shared__ float red[256];
  __shared__ float mrow[QB], invr[QB];
  int qt = blockIdx.x, h = blockIdx.y, b = blockIdx.z;
  int tid = threadIdx.x;
  int q0 = qt * QB;
  const float* base = qkv + (size_t)(b * SQ) * (3 * DM);
  {
    int qi = tid >> 4, d4 = (tid & 15) * 4;
    *(float4*)&Qs[qi][d4] = *(const float4*)&base[(size_t)(q0 + qi) * (3 * DM) + h * HD + d4];
  }
  // scores, 4 K-tiles of 128 rows
  for (int kt = 0; kt < 4; ++kt) {
    __syncthreads();
    {
      int kk = tid >> 4, d4 = (tid & 15) * 4;
#pragma unroll
      for (int i = 0; i < 8; ++i)
        *(float4*)&KVs[kk + 16 * i][d4] =
            *(const float4*)&base[(size_t)(kt * 128 + kk + 16 * i) * (3 * DM) + DM + h * HD + d4];
    }
    __syncthreads();
    int q2 = tid >> 5, k4 = tid & 31;
    float a0[4] = {}, a1[4] = {};
#pragma unroll
    for (int i = 0; i < 16; ++i) {
      float4 qa = *(float4*)&Qs[2 * q2][4 * i];
      float4 qb = *(float4*)&Qs[2 * q2 + 1][4 * i];
#pragma unroll
      for (int j = 0; j < 4; ++j) {
        float4 kv = *(float4*)&KVs[k4 + 32 * j][4 * i];
        a0[j] += qa.x * kv.x + qa.y * kv.y + qa.z * kv.z + qa.w * kv.w;
        a1[j] += qb.x * kv.x + qb.y * kv.y + qb.z * kv.z + qb.w * kv.w;
      }
    }
#pragma unroll
    for (int j = 0; j < 4; ++j) {
      sc[2 * q2][kt * 128 + 32 * j + k4] = a0[j] * 0.125f;
      sc[2 * q2 + 1][kt * 128 + 32 * j + k4] = a1[j] * 0.125f;
    }
  }
  __syncthreads();
  // softmax
  int row = tid & 15, seg = tid >> 4;
  float m = -1e30f;
  for (int i = 0; i < 32; ++i) m = fmaxf(m, sc[row][seg + 16 * i]);
  red[tid] = m; __syncthreads();
  if (tid < QB) {
    float mm = red[tid];
#pragma unroll
    for (int j = 1; j < 16; ++j) mm = fmaxf(mm, red[tid + 16 * j]);
    mrow[tid] = mm;
  }
  __syncthreads();
  m = mrow[row];
  float s = 0.f;
  for (int i = 0; i < 32; ++i) {
    int c = seg + 16 * i;
    float e = expf(sc[row][c] - m);
    sc[row][c] = e; s += e;
  }
  red[tid] = s; __syncthreads();
  if (tid < QB) {
    float ss = red[tid];
#pragma unroll
    for (int j = 1; j < 16; ++j) ss += red[tid + 16 * j];
    invr[tid] = 1.0f / ss;
  }
  // PV, 4 V-tiles (KVs reused)
  float4 o = {0.f, 0.f, 0.f, 0.f};
  int q = tid >> 4, d4 = (tid & 15) * 4;
  for (int vt = 0; vt < 4; ++vt) {
    __syncthreads();
    {
      int kk = tid >> 4, dd = (tid & 15) * 4;
#pragma unroll
      for (int i = 0; i < 8; ++i)
        *(float4*)&KVs[kk + 16 * i][dd] =
            *(const float4*)&base[(size_t)(vt * 128 + kk + 16 * i) * (3 * DM) + 2 * DM + h * HD + dd];
    }
    __syncthreads();
    for (int kk = 0; kk < 128; ++kk) {
      float w = sc[q][vt * 128 + kk];
      float4 v = *(float4*)&KVs[kk][d4];
      o.x += w * v.x; o.y += w * v.y; o.z += w * v.z; o.w += w * v.w;
    }
  }
  float iv = invr[q];
  o.x *= iv; o.y *= iv; o.z *= iv; o.w *= iv;
  *(float4*)&O[(size_t)(b * SQ + q0 + q) * DM + h * HD + d4] = o;
}

// ================= split-precision helpers =================
__global__ __launch_bounds__(256) void k_rmsnorm_sb(const float* __restrict__ x,
    const float* __restrict__ w, float* __restrict__ y,
    ushort* __restrict__ yh, ushort* __restrict__ yl) {
  __shared__ float red[256];
  int t = blockIdx.x, tid = threadIdx.x;
  float ss = 0.f;
  for (int d = tid; d < DM; d += 256) { float v = x[t * DM + d]; ss += v * v; }
  red[tid] = ss; __syncthreads();
  for (int s = 128; s > 0; s >>= 1) { if (tid < s) red[tid] += red[tid + s]; __syncthreads(); }
  float inv = 1.0f / sqrtf(red[0] / (float)DM + REPS);
  for (int d = tid; d < DM; d += 256) {
    float v = w[d] * x[t * DM + d] * inv;
    ushort h = f2b(v);
    y[t * DM + d] = v;
    yh[t * DM + d] = h;
    yl[t * DM + d] = f2b(v - b2f(h));
  }
}

__global__ __launch_bounds__(256) void k_split(const float* __restrict__ in,
    ushort* __restrict__ oh, ushort* __restrict__ ol) {
  int t = blockIdx.x;
  for (int d = threadIdx.x; d < DM; d += 256) {
    float v = in[(size_t)t * DM + d];
    ushort h = f2b(v);
    oh[(size_t)t * DM + d] = h;
    ol[(size_t)t * DM + d] = f2b(v - b2f(h));
  }
}

// plain bf16 pieces (verified LM-head path)
__global__ __launch_bounds__(256) void k_rmsnorm_b(const float* __restrict__ x,
    const float* __restrict__ w, ushort* __restrict__ y) {
  __shared__ float red[256];
  int t = blockIdx.x, tid = threadIdx.x;
  float ss = 0.f;
  for (int d = tid; d < DM; d += 256) { float v = x[t * DM + d]; ss += v * v; }
  red[tid] = ss; __syncthreads();
  for (int s = 128; s > 0; s >>= 1) { if (tid < s) red[tid] += red[tid + s]; __syncthreads(); }
  float inv = 1.0f / sqrtf(red[0] / (float)DM + REPS);
  for (int d = tid; d < DM; d += 256)
    y[t * DM + d] = f2b(w[d] * x[t * DM + d] * inv);
}

__global__ __launch_bounds__(256) void k_tconv(const float* __restrict__ in,
    ushort* __restrict__ out, int K, int ns, int mode) {
  __shared__ float tile[32][33];
  int n0 = blockIdx.x * 32, k0 = blockIdx.y * 32;
  int c = threadIdx.x & 31, rq = threadIdx.x >> 5;
#pragma unroll
  for (int rr = rq; rr < 32; rr += 8)
    tile[rr][c] = in[(size_t)(k0 + rr) * ns + n0 + c];
  __syncthreads();
#pragma unroll
  for (int rr = rq; rr < 32; rr += 8) {
    int n = n0 + rr;
    int orow = (mode == 0) ? n : (((n >> 4) << 5) + ((mode == 1) ? 0 : 16) + (n & 15));
    out[(size_t)orow * K + k0 + c] = f2b(tile[c][rr]);
  }
}

// ================= GEMMs =================
#define EPI_RES  1
#define EPI_F32  2
#define EPI_GU   3
#define EPI_DOWN 4
#define MODE_B   0
#define MODE_QKV 1
#define MODE_GU  2

// r5-verified single-bf16 GEMM (LM head)
template<int EPI, int RM>
__global__ __launch_bounds__(256) void k_gmm(
    const ushort* __restrict__ A, const ushort* __restrict__ Bt,
    ushort* __restrict__ Cb, float* __restrict__ Cf,
    int M, int K, int ldc, int e_arg,
    const int* __restrict__ slot, const int* __restrict__ counts,
    const int* __restrict__ offs) {
  (void)e_arg; (void)slot; (void)counts; (void)offs; (void)Cb;
  int cnt = M;
  int m0 = blockIdx.y * 128;
  if (m0 >= cnt) return;
  int n0 = blockIdx.x * 128;
  __shared__ __align__(16) ushort As[128 * 40];
  __shared__ __align__(16) ushort Bs[128 * 40];
  int tid = threadIdx.x;
  int lane = tid & 63;
  int wave = tid >> 6;
  int wr = wave >> 1, wc = wave & 1;
  int ar1 = tid >> 2, ar2 = ar1 + 64, kc = tid & 3;
  const ushort* Arow1 = A + (size_t)(m0 + ar1) * K;
  const ushort* Arow2 = A + (size_t)(m0 + ar2) * K;
  const ushort* Brow1 = Bt + (size_t)(n0 + ar1) * K;
  const ushort* Brow2 = Bt + (size_t)(n0 + ar2) * K;
  f32x4 zr = {0.f, 0.f, 0.f, 0.f};
  f32x4 acc[4][4];
#pragma unroll
  for (int i = 0; i < 4; ++i)
#pragma unroll
    for (int j = 0; j < 4; ++j) acc[i][j] = zr;
  int rl = lane & 15, g = lane >> 4;
  for (int k0 = 0; k0 < K; k0 += 32) {
    s16x8 va1 = *(const s16x8*)(Arow1 + k0 + kc * 8);
    s16x8 va2 = *(const s16x8*)(Arow2 + k0 + kc * 8);
    s16x8 vb1 = *(const s16x8*)(Brow1 + k0 + kc * 8);
    s16x8 vb2 = *(const s16x8*)(Brow2 + k0 + kc * 8);
    __syncthreads();
    *(s16x8*)&As[ar1 * 40 + kc * 8] = va1;
    *(s16x8*)&As[ar2 * 40 + kc * 8] = va2;
    *(s16x8*)&Bs[ar1 * 40 + kc * 8] = vb1;
    *(s16x8*)&Bs[ar2 * 40 + kc * 8] = vb2;
    __syncthreads();
    s16x8 av[4], bv[4];
#pragma unroll
    for (int mi = 0; mi < 4; ++mi)
      av[mi] = *(const s16x8*)&As[(wr * 64 + mi * 16 + rl) * 40 + g * 8];
#pragma unroll
    for (int ni = 0; ni < 4; ++ni)
      bv[ni] = *(const s16x8*)&Bs[(wc * 64 + ni * 16 + rl) * 40 + g * 8];
#pragma unroll
    for (int mi = 0; mi < 4; ++mi)
#pragma unroll
      for (int ni = 0; ni < 4; ++ni)
        acc[mi][ni] = __builtin_amdgcn_mfma_f32_16x16x32_bf16(av[mi], bv[ni], acc[mi][ni], 0, 0, 0);
  }
  int rg4 = (lane >> 4) * 4;
#pragma unroll
  for (int mi = 0; mi < 4; ++mi)
#pragma unroll
    for (int rg = 0; rg < 4; ++rg) {
      int rloc = m0 + wr * 64 + mi * 16 + rg4 + rg;
#pragma unroll
      for (int ni = 0; ni < 4; ++ni)
        Cf[(size_t)rloc * ldc + n0 + wc * 64 + ni * 16 + rl] = acc[mi][ni][rg];
    }
}

// split-precision GEMM, B read directly from fp32 weights (converted during staging).
// MODE_B: B0[+e*bstride] is [K][ldb]; MODE_QKV: 3 mats, tile x -> mat x/6, col (x%6)*128;
// MODE_GU: B0=gate, B1=up [+e*bstride], interleaved 16-col blocks (matches EPI_GU pairing).
template<int MODE, int EPI, int RM>
__global__ __launch_bounds__(256) void k_gmm_f(
    const ushort* __restrict__ Ah, const ushort* __restrict__ Al,
    const float* __restrict__ B0, const float* __restrict__ B1, const float* __restrict__ B2,
    long long bstride, ushort* __restrict__ Ch, ushort* __restrict__ Cl, float* __restrict__ Cf,
    int M, int K, int ldb, int ldc,
    const int* __restrict__ slot, const int* __restrict__ counts,
    const int* __restrict__ offs) {
  int e = blockIdx.z;
  int cnt = (RM == 0) ? M : counts[e];
  int m0 = blockIdx.y * 128;
  if (m0 >= cnt) return;
  int x = blockIdx.x;
  int n0 = x * 128;
  int off = (RM == 0) ? 0 : offs[e];

  __shared__ __align__(16) ushort Ahs[128 * 40];
  __shared__ __align__(16) ushort Als[128 * 40];
  __shared__ __align__(16) ushort Bhs[128 * 40];
  __shared__ __align__(16) ushort Bls[128 * 40];

  int tid = threadIdx.x;
  int wave = tid >> 6, lane = tid & 63;
  int wr = wave >> 1, wc = wave & 1;

  // A staging (r11-verified pattern)
  int ar1 = tid >> 2, ar2 = ar1 + 64, kc = tid & 3;
  size_t aoff1, aoff2;
  if (RM == 0) {
    aoff1 = (size_t)(m0 + ar1) * K;
    aoff2 = (size_t)(m0 + ar2) * K;
  } else if (RM == 1) {
    aoff1 = (size_t)slot[e * TT + min(m0 + ar1, cnt - 1)] * K;
    aoff2 = (size_t)slot[e * TT + min(m0 + ar2, cnt - 1)] * K;
  } else {
    aoff1 = (size_t)(off + min(m0 + ar1, cnt - 1)) * K;
    aoff2 = (size_t)(off + min(m0 + ar2, cnt - 1)) * K;
  }

  // B staging source pointers: thread covers rows rB and rB+64 (of B^T tile), k-octet ko
  int rB = tid & 63, ko = tid >> 6;
  const float* bsrc0;
  const float* bsrc1;
  if (MODE == MODE_QKV) {
    int mat = x / 6;
    const float* Bm = (mat == 0) ? B0 : ((mat == 1) ? B1 : B2);
    int colbase = (x % 6) * 128;
    bsrc0 = Bm + colbase + rB;
    bsrc1 = Bm + colbase + rB + 64;
  } else if (MODE == MODE_GU) {
    const float* Bg = B0 + (size_t)e * bstride;
    const float* Bu = B1 + (size_t)e * bstride;
    int cb = x * 64;
    int r0 = rB, r1 = rB + 64;
    bsrc0 = (((r0 >> 4) & 1) ? Bu : Bg) + cb + (((r0 >> 5) << 4) | (r0 & 15));
    bsrc1 = (((r1 >> 4) & 1) ? Bu : Bg) + cb + (((r1 >> 5) << 4) | (r1 & 15));
  } else {
    const float* Bm = B0 + (size_t)e * bstride;
    bsrc0 = Bm + n0 + rB;
    bsrc1 = Bm + n0 + rB + 64;
  }

  f32x4 zr = {0.f, 0.f, 0.f, 0.f};
  f32x4 acc[4][4];
#pragma unroll
  for (int i = 0; i < 4; ++i)
#pragma unroll
    for (int j = 0; j < 4; ++j) acc[i][j] = zr;

  int rl = lane & 15, g = lane >> 4;
  for (int k0 = 0; k0 < K; k0 += 32) {
    s16x8 vah1 = *(const s16x8*)(Ah + aoff1 + k0 + kc * 8);
    s16x8 vah2 = *(const s16x8*)(Ah + aoff2 + k0 + kc * 8);
    s16x8 val1 = *(const s16x8*)(Al + aoff1 + k0 + kc * 8);
    s16x8 val2 = *(const s16x8*)(Al + aoff2 + k0 + kc * 8);
    float v0[8], v1[8];
#pragma unroll
    for (int i = 0; i < 8; ++i) {
      v0[i] = bsrc0[(size_t)(k0 + ko * 8 + i) * ldb];
      v1[i] = bsrc1[(size_t)(k0 + ko * 8 + i) * ldb];
    }
    __syncthreads();
    *(s16x8*)&Ahs[ar1 * 40 + kc * 8] = vah1;
    *(s16x8*)&Ahs[ar2 * 40 + kc * 8] = vah2;
    *(s16x8*)&Als[ar1 * 40 + kc * 8] = val1;
    *(s16x8*)&Als[ar2 * 40 + kc * 8] = val2;
    s16x8 h0, l0, h1, l1;
#pragma unroll
    for (int i = 0; i < 8; ++i) {
      ushort h = f2b(v0[i]);
      h0[i] = (short)h; l0[i] = (short)f2b(v0[i] - b2f(h));
      h = f2b(v1[i]);
      h1[i] = (short)h; l1[i] = (short)f2b(v1[i] - b2f(h));
    }
    *(s16x8*)&Bhs[rB * 40 + ko * 8] = h0;
    *(s16x8*)&Bls[rB * 40 + ko * 8] = l0;
    *(s16x8*)&Bhs[(rB + 64) * 40 + ko * 8] = h1;
    *(s16x8*)&Bls[(rB + 64) * 40 + ko * 8] = l1;
    __syncthreads();
#pragma unroll
    for (int mi = 0; mi < 4; ++mi) {
      int ra = (wr * 64 + mi * 16 + rl) * 40 + g * 8;
      s16x8 avh = *(const s16x8*)&Ahs[ra];
      s16x8 avl = *(const s16x8*)&Als[ra];
#pragma unroll
      for (int ni = 0; ni < 4; ++ni) {
        int rb = (wc * 64 + ni * 16 + rl) * 40 + g * 8;
        s16x8 bvh = *(const s16x8*)&Bhs[rb];
        s16x8 bvl = *(const s16x8*)&Bls[rb];
        f32x4 a = acc[mi][ni];
        a = __builtin_amdgcn_mfma_f32_16x16x32_bf16(avl, bvh, a, 0, 0, 0);
        a = __builtin_amdgcn_mfma_f32_16x16x32_bf16(avh, bvl, a, 0, 0, 0);
        a = __builtin_amdgcn_mfma_f32_16x16x32_bf16(avh, bvh, a, 0, 0, 0);
        acc[mi][ni] = a;
      }
    }
  }

  int rg4 = (lane >> 4) * 4;
#pragma unroll
  for (int mi = 0; mi < 4; ++mi) {
#pragma unroll
    for (int rg = 0; rg < 4; ++rg) {
      int rloc = m0 + wr * 64 + mi * 16 + rg4 + rg;
      if ((EPI == EPI_GU || EPI == EPI_DOWN) && rloc >= cnt) continue;
      if (EPI == EPI_GU) {
#pragma unroll
        for (int ni = 0; ni < 4; ni += 2) {
          float gv = acc[mi][ni][rg], uv = acc[mi][ni + 1][rg];
          float hv = gv / (1.f + __expf(-gv)) * uv;
          int fq = (n0 + wc * 64 + ni * 16) >> 5;
          size_t ix = (size_t)(off + rloc) * ldc + fq * 16 + rl;
          ushort h = f2b(hv);
          Ch[ix] = h;
          Cl[ix] = f2b(hv - b2f(h));
        }
      } else if (EPI == EPI_RES) {
#pragma unroll
        for (int ni = 0; ni < 4; ++ni) {
          size_t ix = (size_t)rloc * ldc + n0 + wc * 64 + ni * 16 + rl;
          Cf[ix] += acc[mi][ni][rg];
        }
      } else if (EPI == EPI_F32) {
#pragma unroll
        for (int ni = 0; ni < 4; ++ni)
          Cf[(size_t)rloc * ldc + n0 + wc * 64 + ni * 16 + rl] = acc[mi][ni][rg];
      } else {  // EPI_DOWN
#pragma unroll
        for (int ni = 0; ni < 4; ++ni)
          Cf[(size_t)(off + rloc) * ldc + n0 + wc * 64 + ni * 16 + rl] = acc[mi][ni][rg];
      }
    }
  }
}

extern "C" void kernel_launch(void* const* d_in, const int* in_sizes, int n_in,
                              void* d_out, int out_size, void* d_ws, size_t ws_size,
                              hipStream_t stream) {
  (void)in_sizes; (void)n_in; (void)out_size; (void)ws_size;
  const int*   ids = (const int*)d_in[0];
  const float* tok = (const float*)d_in[1];
  const float* pos = (const float*)d_in[2];
  const float* wq  = (const float*)d_in[3];
  const float* wk  = (const float*)d_in[4];
  const float* wv  = (const float*)d_in[5];
  const float* wo  = (const float*)d_in[6];
  const float* n1w = (const float*)d_in[7];
  const float* n2w = (const float*)d_in[8];
  const float* rw  = (const float*)d_in[9];
  const float* gw  = (const float*)d_in[10];
  const float* uw  = (const float*)d_in[11];
  const float* dw  = (const float*)d_in[12];
  const float* fnw = (const float*)d_in[13];
  const float* lmw = (const float*)d_in[14];
  float* out = (float*)d_out;

  char* p = (char*)d_ws;
  auto alloc = [&](size_t bytes) { char* r = p; p += (bytes + 255) & ~(size_t)255; return r; };
  float*  x    = (float*)alloc((size_t)TT * DM * 4);
  float*  xn   = (float*)alloc((size_t)TT * DM * 4);
  ushort* xh   = (ushort*)alloc((size_t)TT * DM * 2);
  ushort* xl   = (ushort*)alloc((size_t)TT * DM * 2);
  float*  qkv  = (float*)alloc((size_t)TT * 3 * DM * 4);
  float*  ao   = (float*)alloc((size_t)TT * DM * 4);
  ushort* aoh  = (ushort*)alloc((size_t)TT * DM * 2);
  ushort* aol  = (ushort*)alloc((size_t)TT * DM * 2);
  ushort* Hh   = (ushort*)alloc((size_t)2 * TT * FFD * 2);
  ushort* Hl   = (ushort*)alloc((size_t)2 * TT * FFD * 2);
  float*  eo   = (float*)alloc((size_t)2 * TT * DM * 4);
  float*  topw = (float*)alloc((size_t)2 * TT * 4);
  int* topi    = (int*)alloc((size_t)2 * TT * 4);
  int* posb    = (int*)alloc((size_t)2 * TT * 4);
  int* slot    = (int*)alloc((size_t)NE * TT * 4);
  int* counts  = (int*)alloc(256);
  int* offs    = (int*)alloc(256);
  ushort* wlm  = (ushort*)alloc((size_t)LMC * DM * 2);  // LM-head chunk Bt
  ushort* xnb  = (ushort*)alloc((size_t)TT * DM * 2);
  // total ~52 MB

  k_embed<<<TT, 256, 0, stream>>>(ids, tok, pos, x);
  for (int l = 0; l < NL; ++l) {
    // attention: split QKV GEMM (weights read fp32, converted in-kernel) -> tiled fp32 core -> split O-proj
    k_rmsnorm_sb<<<TT, 256, 0, stream>>>(x, n1w + l * DM, xn, xh, xl);
    k_gmm_f<MODE_QKV, EPI_F32, 0><<<dim3(18, 8, 1), 256, 0, stream>>>(
        xh, xl, wq + (size_t)l * DM * DM, wk + (size_t)l * DM * DM, wv + (size_t)l * DM * DM,
        0, nullptr, nullptr, qkv, TT, DM, DM, 3 * DM, nullptr, nullptr, nullptr);
    k_attn2<<<dim3(SQ / QB, NH, NB), 256, 0, stream>>>(qkv, ao);
    k_split<<<TT, 256, 0, stream>>>(ao, aoh, aol);
    k_gmm_f<MODE_B, EPI_RES, 0><<<dim3(6, 8, 1), 256, 0, stream>>>(
        aoh, aol, wo + (size_t)l * DM * DM, nullptr, nullptr,
        0, nullptr, nullptr, x, TT, DM, DM, DM, nullptr, nullptr, nullptr);

    // MoE: fp32 routing + batched split expert GEMMs (no weight conversion passes)
    k_rmsnorm_sb<<<TT, 256, 0, stream>>>(x, n2w + l * DM, xn, xh, xl);
    k_zero8<<<1, 64, 0, stream>>>(counts);
    k_router<<<TT, 64, 0, stream>>>(xn, rw + (size_t)l * DM * NE, topi, topw, posb, slot, counts);
    k_offsets<<<1, 1, 0, stream>>>(counts, offs);
    k_gmm_f<MODE_GU, EPI_GU, 1><<<dim3(32, 8, NE), 256, 0, stream>>>(
        xh, xl, gw + (size_t)l * NE * DM * FFD, uw + (size_t)l * NE * DM * FFD, nullptr,
        (long long)DM * FFD, Hh, Hl, nullptr, TT, DM, FFD, FFD, slot, counts, offs);
    k_gmm_f<MODE_B, EPI_DOWN, 2><<<dim3(6, 8, NE), 256, 0, stream>>>(
        Hh, Hl, dw + (size_t)l * NE * FFD * DM, nullptr, nullptr,
        (long long)FFD * DM, nullptr, nullptr, eo, TT, FFD, DM, DM, slot, counts, offs);
    k_combine<<<TT, 256, 0, stream>>>(eo, topi, topw, posb, offs, x);
  }

  // LM head: r5/r11-verified pure-bf16 path (after all routing)
  k_rmsnorm_b<<<TT, 256, 0, stream>>>(x, fnw, xnb);
  for (int c = 0; c < NV / LMC; ++c) {
    k_tconv<<<dim3(LMC / 32, 24), 256, 0, stream>>>(lmw + c * LMC, wlm, DM, NV, 0);
    k_gmm<EPI_F32, 0><<<dim3(LMC / 128, 8), 256, 0, stream>>>(
        xnb, wlm, nullptr, out + c * LMC, TT, DM, NV, 0, nullptr, nullptr, nullptr);
  }
}

// Round 14
// 1649.771 us; speedup vs baseline: 4.0806x; 1.2389x over previous
//
#include <hip/hip_runtime.h>
#include <math.h>

#define TT   1024
#define DM   768
#define NH   12
#define HD   64
#define FFD  2048
#define NE   8
#define SQ   512
#define NB   2
#define NL   4
#define NV   32000
#define REPS 1e-6f
#define QB   16
#define LMC  3200

typedef float f32x4 __attribute__((ext_vector_type(4)));
typedef short s16x8 __attribute__((ext_vector_type(8)));

__device__ __forceinline__ float b2f(ushort u) {
  return __uint_as_float(((unsigned)u) << 16);
}
__device__ __forceinline__ ushort f2b(float f) {
  unsigned i = __float_as_uint(f);
  return (ushort)((i + 0x7FFFu + ((i >> 16) & 1u)) >> 16);
}

// ================= small kernels (verified) =================
__global__ __launch_bounds__(256) void k_embed(const int* __restrict__ ids,
    const float* __restrict__ tok, const float* __restrict__ pos, float* __restrict__ x) {
  int t = blockIdx.x; int s = t % SQ; int id = ids[t];
  for (int d = threadIdx.x; d < DM; d += 256)
    x[t * DM + d] = tok[(size_t)id * DM + d] + pos[s * DM + d];
}

__global__ __launch_bounds__(64) void k_router(const float* __restrict__ xn,
    const float* __restrict__ rw, int* __restrict__ topi, float* __restrict__ topw,
    int* __restrict__ posb, int* __restrict__ slot, int* __restrict__ counts) {
  int t = blockIdx.x, l = threadIdx.x;
  float acc[NE] = {};
  for (int d = l; d < DM; d += 64) {
    float xv = xn[t * DM + d];
    const float* r = &rw[d * NE];
#pragma unroll
    for (int e = 0; e < NE; ++e) acc[e] += xv * r[e];
  }
#pragma unroll
  for (int off = 32; off > 0; off >>= 1)
#pragma unroll
    for (int e = 0; e < NE; ++e) acc[e] += __shfl_down(acc[e], off, 64);
  if (l == 0) {
    float mx = acc[0];
#pragma unroll
    for (int e = 1; e < NE; ++e) mx = fmaxf(mx, acc[e]);
    float p[NE], sum = 0.f;
#pragma unroll
    for (int e = 0; e < NE; ++e) { p[e] = expf(acc[e] - mx); sum += p[e]; }
#pragma unroll
    for (int e = 0; e < NE; ++e) p[e] /= sum;
    int i0 = 0;
    for (int e = 1; e < NE; ++e) if (p[e] > p[i0]) i0 = e;
    int i1 = (i0 == 0) ? 1 : 0;
    for (int e = 0; e < NE; ++e) if (e != i0 && p[e] > p[i1]) i1 = e;
    float w0 = p[i0], w1 = p[i1], inv = 1.f / (w0 + w1);
    w0 *= inv; w1 *= inv;
    int p0 = atomicAdd(&counts[i0], 1);
    int p1 = atomicAdd(&counts[i1], 1);
    topi[2 * t] = i0; topi[2 * t + 1] = i1;
    topw[2 * t] = w0; topw[2 * t + 1] = w1;
    posb[2 * t] = p0; posb[2 * t + 1] = p1;
    slot[i0 * TT + p0] = t; slot[i1 * TT + p1] = t;
  }
}

__global__ void k_zero8(int* c) { if (threadIdx.x < NE) c[threadIdx.x] = 0; }

__global__ void k_offsets(const int* __restrict__ counts, int* __restrict__ off) {
  int a = 0;
  for (int e = 0; e < NE; ++e) { off[e] = a; a += counts[e]; }
  off[NE] = a;
}

__global__ __launch_bounds__(256) void k_combine(const float* __restrict__ eo,
    const int* __restrict__ topi, const float* __restrict__ topw,
    const int* __restrict__ posb, const int* __restrict__ offs, float* __restrict__ x) {
  int t = blockIdx.x;
  int r0 = offs[topi[2 * t]] + posb[2 * t];
  int r1 = offs[topi[2 * t + 1]] + posb[2 * t + 1];
  float w0 = topw[2 * t], w1 = topw[2 * t + 1];
  for (int d = threadIdx.x; d < DM; d += 256)
    x[t * DM + d] += w0 * eo[(size_t)r0 * DM + d] + w1 * eo[(size_t)r1 * DM + d];
}

// ================= tiled fp32 attention (r12-verified) =================
__global__ __launch_bounds__(256) void k_attn2(const float* __restrict__ qkv,
    float* __restrict__ O) {
  __shared__ float Qs[QB][64];
  __shared__ float KVs[128][68];
  __shared__ float sc[QB][516];
  __shared__ float red[256];
  __shared__ float mrow[QB], invr[QB];
  int qt = blockIdx.x, h = blockIdx.y, b = blockIdx.z;
  int tid = threadIdx.x;
  int q0 = qt * QB;
  const float* base = qkv + (size_t)(b * SQ) * (3 * DM);
  {
    int qi = tid >> 4, d4 = (tid & 15) * 4;
    *(float4*)&Qs[qi][d4] = *(const float4*)&base[(size_t)(q0 + qi) * (3 * DM) + h * HD + d4];
  }
  for (int kt = 0; kt < 4; ++kt) {
    __syncthreads();
    {
      int kk = tid >> 4, d4 = (tid & 15) * 4;
#pragma unroll
      for (int i = 0; i < 8; ++i)
        *(float4*)&KVs[kk + 16 * i][d4] =
            *(const float4*)&base[(size_t)(kt * 128 + kk + 16 * i) * (3 * DM) + DM + h * HD + d4];
    }
    __syncthreads();
    int q2 = tid >> 5, k4 = tid & 31;
    float a0[4] = {}, a1[4] = {};
#pragma unroll
    for (int i = 0; i < 16; ++i) {
      float4 qa = *(float4*)&Qs[2 * q2][4 * i];
      float4 qb = *(float4*)&Qs[2 * q2 + 1][4 * i];
#pragma unroll
      for (int j = 0; j < 4; ++j) {
        float4 kv = *(float4*)&KVs[k4 + 32 * j][4 * i];
        a0[j] += qa.x * kv.x + qa.y * kv.y + qa.z * kv.z + qa.w * kv.w;
        a1[j] += qb.x * kv.x + qb.y * kv.y + qb.z * kv.z + qb.w * kv.w;
      }
    }
#pragma unroll
    for (int j = 0; j < 4; ++j) {
      sc[2 * q2][kt * 128 + 32 * j + k4] = a0[j] * 0.125f;
      sc[2 * q2 + 1][kt * 128 + 32 * j + k4] = a1[j] * 0.125f;
    }
  }
  __syncthreads();
  int row = tid & 15, seg = tid >> 4;
  float m = -1e30f;
  for (int i = 0; i < 32; ++i) m = fmaxf(m, sc[row][seg + 16 * i]);
  red[tid] = m; __syncthreads();
  if (tid < QB) {
    float mm = red[tid];
#pragma unroll
    for (int j = 1; j < 16; ++j) mm = fmaxf(mm, red[tid + 16 * j]);
    mrow[tid] = mm;
  }
  __syncthreads();
  m = mrow[row];
  float s = 0.f;
  for (int i = 0; i < 32; ++i) {
    int c = seg + 16 * i;
    float e = expf(sc[row][c] - m);
    sc[row][c] = e; s += e;
  }
  red[tid] = s; __syncthreads();
  if (tid < QB) {
    float ss = red[tid];
#pragma unroll
    for (int j = 1; j < 16; ++j) ss += red[tid + 16 * j];
    invr[tid] = 1.0f / ss;
  }
  float4 o = {0.f, 0.f, 0.f, 0.f};
  int q = tid >> 4, d4 = (tid & 15) * 4;
  for (int vt = 0; vt < 4; ++vt) {
    __syncthreads();
    {
      int kk = tid >> 4, dd = (tid & 15) * 4;
#pragma unroll
      for (int i = 0; i < 8; ++i)
        *(float4*)&KVs[kk + 16 * i][dd] =
            *(const float4*)&base[(size_t)(vt * 128 + kk + 16 * i) * (3 * DM) + 2 * DM + h * HD + dd];
    }
    __syncthreads();
    for (int kk = 0; kk < 128; ++kk) {
      float w = sc[q][vt * 128 + kk];
      float4 v = *(float4*)&KVs[kk][d4];
      o.x += w * v.x; o.y += w * v.y; o.z += w * v.z; o.w += w * v.w;
    }
  }
  float iv = invr[q];
  o.x *= iv; o.y *= iv; o.z *= iv; o.w *= iv;
  *(float4*)&O[(size_t)(b * SQ + q0 + q) * DM + h * HD + d4] = o;
}

// ================= split-precision helpers (verified) =================
__global__ __launch_bounds__(256) void k_rmsnorm_sb(const float* __restrict__ x,
    const float* __restrict__ w, float* __restrict__ y,
    ushort* __restrict__ yh, ushort* __restrict__ yl) {
  __shared__ float red[256];
  int t = blockIdx.x, tid = threadIdx.x;
  float ss = 0.f;
  for (int d = tid; d < DM; d += 256) { float v = x[t * DM + d]; ss += v * v; }
  red[tid] = ss; __syncthreads();
  for (int s = 128; s > 0; s >>= 1) { if (tid < s) red[tid] += red[tid + s]; __syncthreads(); }
  float inv = 1.0f / sqrtf(red[0] / (float)DM + REPS);
  for (int d = tid; d < DM; d += 256) {
    float v = w[d] * x[t * DM + d] * inv;
    ushort h = f2b(v);
    y[t * DM + d] = v;
    yh[t * DM + d] = h;
    yl[t * DM + d] = f2b(v - b2f(h));
  }
}

__global__ __launch_bounds__(256) void k_split(const float* __restrict__ in,
    ushort* __restrict__ oh, ushort* __restrict__ ol) {
  int t = blockIdx.x;
  for (int d = threadIdx.x; d < DM; d += 256) {
    float v = in[(size_t)t * DM + d];
    ushort h = f2b(v);
    oh[(size_t)t * DM + d] = h;
    ol[(size_t)t * DM + d] = f2b(v - b2f(h));
  }
}

__global__ __launch_bounds__(256) void k_rmsnorm_b(const float* __restrict__ x,
    const float* __restrict__ w, ushort* __restrict__ y) {
  __shared__ float red[256];
  int t = blockIdx.x, tid = threadIdx.x;
  float ss = 0.f;
  for (int d = tid; d < DM; d += 256) { float v = x[t * DM + d]; ss += v * v; }
  red[tid] = ss; __syncthreads();
  for (int s = 128; s > 0; s >>= 1) { if (tid < s) red[tid] += red[tid + s]; __syncthreads(); }
  float inv = 1.0f / sqrtf(red[0] / (float)DM + REPS);
  for (int d = tid; d < DM; d += 256)
    y[t * DM + d] = f2b(w[d] * x[t * DM + d] * inv);
}

__global__ __launch_bounds__(256) void k_tconv(const float* __restrict__ in,
    ushort* __restrict__ out, int K, int ns, int mode) {
  __shared__ float tile[32][33];
  int n0 = blockIdx.x * 32, k0 = blockIdx.y * 32;
  int c = threadIdx.x & 31, rq = threadIdx.x >> 5;
#pragma unroll
  for (int rr = rq; rr < 32; rr += 8)
    tile[rr][c] = in[(size_t)(k0 + rr) * ns + n0 + c];
  __syncthreads();
#pragma unroll
  for (int rr = rq; rr < 32; rr += 8) {
    int n = n0 + rr;
    int orow = (mode == 0) ? n : (((n >> 4) << 5) + ((mode == 1) ? 0 : 16) + (n & 15));
    out[(size_t)orow * K + k0 + c] = f2b(tile[c][rr]);
  }
}

// ================= GEMMs =================
#define EPI_RES  1
#define EPI_F32  2
#define EPI_GU   3
#define EPI_DOWN 4
#define MODE_B   0
#define MODE_QKV 1
#define MODE_GU  2

// r5/r12-verified single-bf16 GEMM (LM head)
template<int EPI, int RM>
__global__ __launch_bounds__(256) void k_gmm(
    const ushort* __restrict__ A, const ushort* __restrict__ Bt,
    ushort* __restrict__ Cb, float* __restrict__ Cf,
    int M, int K, int ldc, int e_arg,
    const int* __restrict__ slot, const int* __restrict__ counts,
    const int* __restrict__ offs) {
  (void)e_arg; (void)slot; (void)counts; (void)offs; (void)Cb;
  int cnt = M;
  int m0 = blockIdx.y * 128;
  if (m0 >= cnt) return;
  int n0 = blockIdx.x * 128;
  __shared__ __align__(16) ushort As[128 * 40];
  __shared__ __align__(16) ushort Bs[128 * 40];
  int tid = threadIdx.x;
  int lane = tid & 63;
  int wave = tid >> 6;
  int wr = wave >> 1, wc = wave & 1;
  int ar1 = tid >> 2, ar2 = ar1 + 64, kc = tid & 3;
  const ushort* Arow1 = A + (size_t)(m0 + ar1) * K;
  const ushort* Arow2 = A + (size_t)(m0 + ar2) * K;
  const ushort* Brow1 = Bt + (size_t)(n0 + ar1) * K;
  const ushort* Brow2 = Bt + (size_t)(n0 + ar2) * K;
  f32x4 zr = {0.f, 0.f, 0.f, 0.f};
  f32x4 acc[4][4];
#pragma unroll
  for (int i = 0; i < 4; ++i)
#pragma unroll
    for (int j = 0; j < 4; ++j) acc[i][j] = zr;
  int rl = lane & 15, g = lane >> 4;
  for (int k0 = 0; k0 < K; k0 += 32) {
    s16x8 va1 = *(const s16x8*)(Arow1 + k0 + kc * 8);
    s16x8 va2 = *(const s16x8*)(Arow2 + k0 + kc * 8);
    s16x8 vb1 = *(const s16x8*)(Brow1 + k0 + kc * 8);
    s16x8 vb2 = *(const s16x8*)(Brow2 + k0 + kc * 8);
    __syncthreads();
    *(s16x8*)&As[ar1 * 40 + kc * 8] = va1;
    *(s16x8*)&As[ar2 * 40 + kc * 8] = va2;
    *(s16x8*)&Bs[ar1 * 40 + kc * 8] = vb1;
    *(s16x8*)&Bs[ar2 * 40 + kc * 8] = vb2;
    __syncthreads();
    s16x8 av[4], bv[4];
#pragma unroll
    for (int mi = 0; mi < 4; ++mi)
      av[mi] = *(const s16x8*)&As[(wr * 64 + mi * 16 + rl) * 40 + g * 8];
#pragma unroll
    for (int ni = 0; ni < 4; ++ni)
      bv[ni] = *(const s16x8*)&Bs[(wc * 64 + ni * 16 + rl) * 40 + g * 8];
#pragma unroll
    for (int mi = 0; mi < 4; ++mi)
#pragma unroll
      for (int ni = 0; ni < 4; ++ni)
        acc[mi][ni] = __builtin_amdgcn_mfma_f32_16x16x32_bf16(av[mi], bv[ni], acc[mi][ni], 0, 0, 0);
  }
  int rg4 = (lane >> 4) * 4;
#pragma unroll
  for (int mi = 0; mi < 4; ++mi)
#pragma unroll
    for (int rg = 0; rg < 4; ++rg) {
      int rloc = m0 + wr * 64 + mi * 16 + rg4 + rg;
#pragma unroll
      for (int ni = 0; ni < 4; ++ni)
        Cf[(size_t)rloc * ldc + n0 + wc * 64 + ni * 16 + rl] = acc[mi][ni][rg];
    }
}

// pipelined split-precision GEMM, B read fp32 directly (r13 core, SK paths unused)
template<int BM, int BN, int MODE, int EPI, int RM, int SK, int NBX, int PREC>
__global__ __launch_bounds__(256) void k_gmm2(
    const ushort* __restrict__ Ah, const ushort* __restrict__ Al,
    const float* __restrict__ B0, const float* __restrict__ B1, const float* __restrict__ B2,
    long long bstride, ushort* __restrict__ Ch, ushort* __restrict__ Cl,
    float* __restrict__ Cf, float* __restrict__ Cf2,
    int M, int K, int ldb, int ldc,
    const int* __restrict__ slot, const int* __restrict__ counts,
    const int* __restrict__ offs) {
  constexpr int NEg  = (RM == 0) ? 1 : NE;
  constexpr int P    = NBX * NEg * SK;
  constexpr int Ppad = ((P + 7) / 8) * 8;
  int id = blockIdx.x;
  int m = id / Ppad, pp = id % Ppad;
  if (pp >= P) return;
  int e = pp / (NBX * SK);
  int rr = pp % (NBX * SK);
  int x = rr / SK, sk = rr % SK;

  int cnt = (RM == 0) ? M : counts[e];
  int m0 = m * BM;
  if (m0 >= cnt) return;
  int n0 = x * BN;
  int off = (RM == 0) ? 0 : offs[e];
  int KK = K / SK, kbeg = sk * KK;

  constexpr int WM = (BM == 128) ? 64 : ((BN == 128) ? 64 : 32);
  constexpr int WN = (BM == 128) ? 64 : 32;
  constexpr int MI = WM / 16, NI = WN / 16;

  __shared__ __align__(16) ushort Ahs[BM * 40];
  __shared__ __align__(16) ushort Als[(PREC == 2) ? BM * 40 : 16];
  __shared__ __align__(16) ushort Bhs[BN * 40];
  __shared__ __align__(16) ushort Bls[(PREC == 2) ? BN * 40 : 16];

  int tid = threadIdx.x;
  int wave = tid >> 6, lane = tid & 63;
  int wr, wc;
  if (BM == 128)      { wr = wave >> 1; wc = wave & 1; }
  else if (BN == 128) { wr = 0;         wc = wave;     }
  else                { wr = wave >> 1; wc = wave & 1; }
  int moff;
  if (BM == 64 && BN == 128) moff = 0; else moff = wr * ((BM == 128) ? 64 : 32);
  int noff = wc * WN;

  int arA = tid >> 2, kcA = tid & 3;
  int ar1 = tid >> 2, ar2 = ar1 + 64;
  size_t aoff1 = 0, aoff2 = 0;
  if (BM == 64) {
    int rowi;
    if (RM == 0)      rowi = m0 + arA;
    else if (RM == 1) rowi = slot[e * TT + min(m0 + arA, cnt - 1)];
    else              rowi = off + min(m0 + arA, cnt - 1);
    aoff1 = (size_t)rowi * K;
  } else {
    if (RM == 0) {
      aoff1 = (size_t)(m0 + ar1) * K;
      aoff2 = (size_t)(m0 + ar2) * K;
    } else if (RM == 1) {
      aoff1 = (size_t)slot[e * TT + min(m0 + ar1, cnt - 1)] * K;
      aoff2 = (size_t)slot[e * TT + min(m0 + ar2, cnt - 1)] * K;
    } else {
      aoff1 = (size_t)(off + min(m0 + ar1, cnt - 1)) * K;
      aoff2 = (size_t)(off + min(m0 + ar2, cnt - 1)) * K;
    }
  }

  int rB = tid & 63, ko = tid >> 6;
  auto bcol = [&](int r) -> const float* {
    if (MODE == MODE_QKV) {
      int mat = x / (NBX / 3);
      const float* Bm = (mat == 0) ? B0 : ((mat == 1) ? B1 : B2);
      return Bm + (x % (NBX / 3)) * BN + r;
    } else if (MODE == MODE_GU) {
      const float* Bg = B0 + (size_t)e * bstride;
      const float* Bu = B1 + (size_t)e * bstride;
      return ((((r) >> 4) & 1) ? Bu : Bg) + x * (BN / 2) + ((((r) >> 5) << 4) | ((r) & 15));
    }
    return B0 + (size_t)e * bstride + n0 + r;
  };
  const float* bs0 = bcol(rB);
  const float* bs1 = (BN == 128) ? bcol(rB + 64) : nullptr;

  s16x8 rah1, rah2, ral1, ral2;
  float vb0[8], vb1[8];

  auto loadA = [&](int kk) {
    if (BM == 64) {
      rah1 = *(const s16x8*)(Ah + aoff1 + kbeg + kk + kcA * 8);
      if (PREC == 2) ral1 = *(const s16x8*)(Al + aoff1 + kbeg + kk + kcA * 8);
    } else {
      rah1 = *(const s16x8*)(Ah + aoff1 + kbeg + kk + kcA * 8);
      rah2 = *(const s16x8*)(Ah + aoff2 + kbeg + kk + kcA * 8);
      if (PREC == 2) {
        ral1 = *(const s16x8*)(Al + aoff1 + kbeg + kk + kcA * 8);
        ral2 = *(const s16x8*)(Al + aoff2 + kbeg + kk + kcA * 8);
      }
    }
  };
  auto loadB = [&](int kk) {
#pragma unroll
    for (int i = 0; i < 8; ++i)
      vb0[i] = bs0[(size_t)(kbeg + kk + ko * 8 + i) * ldb];
    if (BN == 128) {
#pragma unroll
      for (int i = 0; i < 8; ++i)
        vb1[i] = bs1[(size_t)(kbeg + kk + ko * 8 + i) * ldb];
    }
  };
  auto storeLDS = [&]() {
    if (BM == 64) {
      *(s16x8*)&Ahs[arA * 40 + kcA * 8] = rah1;
      if (PREC == 2) *(s16x8*)&Als[arA * 40 + kcA * 8] = ral1;
    } else {
      *(s16x8*)&Ahs[ar1 * 40 + kcA * 8] = rah1;
      *(s16x8*)&Ahs[ar2 * 40 + kcA * 8] = rah2;
      if (PREC == 2) {
        *(s16x8*)&Als[ar1 * 40 + kcA * 8] = ral1;
        *(s16x8*)&Als[ar2 * 40 + kcA * 8] = ral2;
      }
    }
    s16x8 h0, l0;
#pragma unroll
    for (int i = 0; i < 8; ++i) {
      ushort h = f2b(vb0[i]);
      h0[i] = (short)h;
      if (PREC == 2) l0[i] = (short)f2b(vb0[i] - b2f(h));
    }
    *(s16x8*)&Bhs[rB * 40 + ko * 8] = h0;
    if (PREC == 2) *(s16x8*)&Bls[rB * 40 + ko * 8] = l0;
    if (BN == 128) {
      s16x8 h1, l1;
#pragma unroll
      for (int i = 0; i < 8; ++i) {
        ushort h = f2b(vb1[i]);
        h1[i] = (short)h;
        if (PREC == 2) l1[i] = (short)f2b(vb1[i] - b2f(h));
      }
      *(s16x8*)&Bhs[(rB + 64) * 40 + ko * 8] = h1;
      if (PREC == 2) *(s16x8*)&Bls[(rB + 64) * 40 + ko * 8] = l1;
    }
  };

  f32x4 zr = {0.f, 0.f, 0.f, 0.f};
  f32x4 acc[MI][NI];
#pragma unroll
  for (int i = 0; i < MI; ++i)
#pragma unroll
    for (int j = 0; j < NI; ++j) acc[i][j] = zr;

  int rl = lane & 15, g = lane >> 4;
  loadA(0); loadB(0);
  for (int k0 = 0; k0 < KK; k0 += 32) {
    __syncthreads();
    storeLDS();
    __syncthreads();
    if (k0 + 32 < KK) { loadA(k0 + 32); loadB(k0 + 32); }
#pragma unroll
    for (int mi = 0; mi < MI; ++mi) {
      int ra = (moff + mi * 16 + rl) * 40 + g * 8;
      s16x8 avh = *(const s16x8*)&Ahs[ra];
      s16x8 avl;
      if (PREC == 2) avl = *(const s16x8*)&Als[ra];
#pragma unroll
      for (int ni = 0; ni < NI; ++ni) {
        int rb = (noff + ni * 16 + rl) * 40 + g * 8;
        s16x8 bvh = *(const s16x8*)&Bhs[rb];
        f32x4 a = acc[mi][ni];
        if (PREC == 2) {
          s16x8 bvl = *(const s16x8*)&Bls[rb];
          a = __builtin_amdgcn_mfma_f32_16x16x32_bf16(avl, bvh, a, 0, 0, 0);
          a = __builtin_amdgcn_mfma_f32_16x16x32_bf16(avh, bvl, a, 0, 0, 0);
        }
        a = __builtin_amdgcn_mfma_f32_16x16x32_bf16(avh, bvh, a, 0, 0, 0);
        acc[mi][ni] = a;
      }
    }
  }

  float* Cfx = (SK == 2 && sk == 1) ? Cf2 : Cf;
  int rg4 = (lane >> 4) * 4;
#pragma unroll
  for (int mi = 0; mi < MI; ++mi) {
#pragma unroll
    for (int rg = 0; rg < 4; ++rg) {
      int rloc = m0 + moff + mi * 16 + rg4 + rg;
      if ((EPI == EPI_GU || EPI == EPI_DOWN) && rloc >= cnt) continue;
      if (EPI == EPI_GU) {
        float gv = acc[mi][0][rg], uv = acc[mi][1][rg];
        float hv = gv / (1.f + __expf(-gv)) * uv;
        int fq = (n0 + noff) >> 5;
        size_t ix = (size_t)(off + rloc) * ldc + fq * 16 + rl;
        ushort h = f2b(hv);
        Ch[ix] = h;
        Cl[ix] = f2b(hv - b2f(h));
      } else if (EPI == EPI_RES) {
#pragma unroll
        for (int ni = 0; ni < NI; ++ni) {
          size_t ix = (size_t)rloc * ldc + n0 + noff + ni * 16 + rl;
          Cf[ix] += acc[mi][ni][rg];
        }
      } else if (EPI == EPI_F32) {
#pragma unroll
        for (int ni = 0; ni < NI; ++ni)
          Cfx[(size_t)rloc * ldc + n0 + noff + ni * 16 + rl] = acc[mi][ni][rg];
      } else {  // EPI_DOWN
#pragma unroll
        for (int ni = 0; ni < NI; ++ni)
          Cfx[(size_t)(off + rloc) * ldc + n0 + noff + ni * 16 + rl] = acc[mi][ni][rg];
      }
    }
  }
}

extern "C" void kernel_launch(void* const* d_in, const int* in_sizes, int n_in,
                              void* d_out, int out_size, void* d_ws, size_t ws_size,
                              hipStream_t stream) {
  (void)in_sizes; (void)n_in; (void)out_size; (void)ws_size;
  const int*   ids = (const int*)d_in[0];
  const float* tok = (const float*)d_in[1];
  const float* pos = (const float*)d_in[2];
  const float* wq  = (const float*)d_in[3];
  const float* wk  = (const float*)d_in[4];
  const float* wv  = (const float*)d_in[5];
  const float* wo  = (const float*)d_in[6];
  const float* n1w = (const float*)d_in[7];
  const float* n2w = (const float*)d_in[8];
  const float* rw  = (const float*)d_in[9];
  const float* gw  = (const float*)d_in[10];
  const float* uw  = (const float*)d_in[11];
  const float* dw  = (const float*)d_in[12];
  const float* fnw = (const float*)d_in[13];
  const float* lmw = (const float*)d_in[14];
  float* out = (float*)d_out;

  char* p = (char*)d_ws;
  auto alloc = [&](size_t bytes) { char* r = p; p += (bytes + 255) & ~(size_t)255; return r; };
  float*  x    = (float*)alloc((size_t)TT * DM * 4);
  float*  xn   = (float*)alloc((size_t)TT * DM * 4);
  ushort* xh   = (ushort*)alloc((size_t)TT * DM * 2);
  ushort* xl   = (ushort*)alloc((size_t)TT * DM * 2);
  float*  qkv  = (float*)alloc((size_t)TT * 3 * DM * 4);
  float*  ao   = (float*)alloc((size_t)TT * DM * 4);
  ushort* aoh  = (ushort*)alloc((size_t)TT * DM * 2);
  ushort* aol  = (ushort*)alloc((size_t)TT * DM * 2);
  ushort* Hh   = (ushort*)alloc((size_t)2 * TT * FFD * 2);
  ushort* Hl   = (ushort*)alloc((size_t)2 * TT * FFD * 2);
  float*  eo   = (float*)alloc((size_t)2 * TT * DM * 4);
  float*  topw = (float*)alloc((size_t)2 * TT * 4);
  int* topi    = (int*)alloc((size_t)2 * TT * 4);
  int* posb    = (int*)alloc((size_t)2 * TT * 4);
  int* slot    = (int*)alloc((size_t)NE * TT * 4);
  int* counts  = (int*)alloc(256);
  int* offs    = (int*)alloc(256);
  ushort* wlm  = (ushort*)alloc((size_t)LMC * DM * 2);
  ushort* xnb  = (ushort*)alloc((size_t)TT * DM * 2);

  k_embed<<<TT, 256, 0, stream>>>(ids, tok, pos, x);
  for (int l = 0; l < NL; ++l) {
    // attention
    k_rmsnorm_sb<<<TT, 256, 0, stream>>>(x, n1w + l * DM, xn, xh, xl);
    k_gmm2<64, 64, MODE_QKV, EPI_F32, 0, 1, 36, 2><<<16 * 40, 256, 0, stream>>>(
        xh, xl, wq + (size_t)l * DM * DM, wk + (size_t)l * DM * DM, wv + (size_t)l * DM * DM,
        0, nullptr, nullptr, qkv, nullptr, TT, DM, DM, 3 * DM, nullptr, nullptr, nullptr);
    k_attn2<<<dim3(SQ / QB, NH, NB), 256, 0, stream>>>(qkv, ao);
    k_split<<<TT, 256, 0, stream>>>(ao, aoh, aol);
    // O-proj: EPI_RES (r11/r12-verified += epilogue), no split-K
    k_gmm2<64, 64, MODE_B, EPI_RES, 0, 1, 12, 2><<<16 * 16, 256, 0, stream>>>(
        aoh, aol, wo + (size_t)l * DM * DM, nullptr, nullptr,
        0, nullptr, nullptr, x, nullptr, TT, DM, DM, DM, nullptr, nullptr, nullptr);

    // MoE
    k_rmsnorm_sb<<<TT, 256, 0, stream>>>(x, n2w + l * DM, xn, xh, xl);
    k_zero8<<<1, 64, 0, stream>>>(counts);
    k_router<<<TT, 64, 0, stream>>>(xn, rw + (size_t)l * DM * NE, topi, topw, posb, slot, counts);
    k_offsets<<<1, 1, 0, stream>>>(counts, offs);
    k_gmm2<64, 128, MODE_GU, EPI_GU, 1, 1, 32, 2><<<16 * 256, 256, 0, stream>>>(
        xh, xl, gw + (size_t)l * NE * DM * FFD, uw + (size_t)l * NE * DM * FFD, nullptr,
        (long long)DM * FFD, Hh, Hl, nullptr, nullptr, TT, DM, FFD, FFD, slot, counts, offs);
    // down: single-K (no split), r12-style combine
    k_gmm2<64, 64, MODE_B, EPI_DOWN, 2, 1, 12, 2><<<16 * 96, 256, 0, stream>>>(
        Hh, Hl, dw + (size_t)l * NE * FFD * DM, nullptr, nullptr,
        (long long)FFD * DM, nullptr, nullptr, eo, nullptr, TT, FFD, DM, DM, slot, counts, offs);
    k_combine<<<TT, 256, 0, stream>>>(eo, topi, topw, posb, offs, x);
  }

  // LM head: r5/r12-verified tconv + k_gmm path
  k_rmsnorm_b<<<TT, 256, 0, stream>>>(x, fnw, xnb);
  for (int c = 0; c < NV / LMC; ++c) {
    k_tconv<<<dim3(LMC / 32, 24), 256, 0, stream>>>(lmw + c * LMC, wlm, DM, NV, 0);
    k_gmm<EPI_F32, 0><<<dim3(LMC / 128, 8), 256, 0, stream>>>(
        xnb, wlm, nullptr, out + c * LMC, TT, DM, NV, 0, nullptr, nullptr, nullptr);
  }
}

// Round 15
// 1485.770 us; speedup vs baseline: 4.5310x; 1.1104x over previous
//
#include <hip/hip_runtime.h>
#include <math.h>

#define TT   1024
#define DM   768
#define NH   12
#define HD   64
#define FFD  2048
#define NE   8
#define SQ   512
#define NB   2
#define NL   4
#define NV   32000
#define REPS 1e-6f
#define QB   16

typedef float f32x4 __attribute__((ext_vector_type(4)));
typedef short s16x8 __attribute__((ext_vector_type(8)));

__device__ __forceinline__ float b2f(ushort u) {
  return __uint_as_float(((unsigned)u) << 16);
}
__device__ __forceinline__ ushort f2b(float f) {
  unsigned i = __float_as_uint(f);
  return (ushort)((i + 0x7FFFu + ((i >> 16) & 1u)) >> 16);
}

// ================= small kernels (verified) =================
__global__ __launch_bounds__(256) void k_embed(const int* __restrict__ ids,
    const float* __restrict__ tok, const float* __restrict__ pos, float* __restrict__ x) {
  int t = blockIdx.x; int s = t % SQ; int id = ids[t];
  for (int d = threadIdx.x; d < DM; d += 256)
    x[t * DM + d] = tok[(size_t)id * DM + d] + pos[s * DM + d];
}

__global__ __launch_bounds__(64) void k_router(const float* __restrict__ xn,
    const float* __restrict__ rw, int* __restrict__ topi, float* __restrict__ topw,
    int* __restrict__ posb, int* __restrict__ slot, int* __restrict__ counts) {
  int t = blockIdx.x, l = threadIdx.x;
  float acc[NE] = {};
  for (int d = l; d < DM; d += 64) {
    float xv = xn[t * DM + d];
    const float* r = &rw[d * NE];
#pragma unroll
    for (int e = 0; e < NE; ++e) acc[e] += xv * r[e];
  }
#pragma unroll
  for (int off = 32; off > 0; off >>= 1)
#pragma unroll
    for (int e = 0; e < NE; ++e) acc[e] += __shfl_down(acc[e], off, 64);
  if (l == 0) {
    float mx = acc[0];
#pragma unroll
    for (int e = 1; e < NE; ++e) mx = fmaxf(mx, acc[e]);
    float p[NE], sum = 0.f;
#pragma unroll
    for (int e = 0; e < NE; ++e) { p[e] = expf(acc[e] - mx); sum += p[e]; }
#pragma unroll
    for (int e = 0; e < NE; ++e) p[e] /= sum;
    int i0 = 0;
    for (int e = 1; e < NE; ++e) if (p[e] > p[i0]) i0 = e;
    int i1 = (i0 == 0) ? 1 : 0;
    for (int e = 0; e < NE; ++e) if (e != i0 && p[e] > p[i1]) i1 = e;
    float w0 = p[i0], w1 = p[i1], inv = 1.f / (w0 + w1);
    w0 *= inv; w1 *= inv;
    int p0 = atomicAdd(&counts[i0], 1);
    int p1 = atomicAdd(&counts[i1], 1);
    topi[2 * t] = i0; topi[2 * t + 1] = i1;
    topw[2 * t] = w0; topw[2 * t + 1] = w1;
    posb[2 * t] = p0; posb[2 * t + 1] = p1;
    slot[i0 * TT + p0] = t; slot[i1 * TT + p1] = t;
  }
}

// combine with inline prefix-sum of counts (replaces offs buffer)
__global__ __launch_bounds__(256) void k_combine(const float* __restrict__ eo,
    const int* __restrict__ topi, const float* __restrict__ topw,
    const int* __restrict__ posb, const int* __restrict__ counts, float* __restrict__ x) {
  int t = blockIdx.x;
  int pre[NE]; int a = 0;
#pragma unroll
  for (int e = 0; e < NE; ++e) { pre[e] = a; a += counts[e]; }
  int r0 = pre[topi[2 * t]] + posb[2 * t];
  int r1 = pre[topi[2 * t + 1]] + posb[2 * t + 1];
  float w0 = topw[2 * t], w1 = topw[2 * t + 1];
  for (int d = threadIdx.x; d < DM; d += 256)
    x[t * DM + d] += w0 * eo[(size_t)r0 * DM + d] + w1 * eo[(size_t)r1 * DM + d];
}

// ================= tiled fp32 attention, split-output epilogue =================
__global__ __launch_bounds__(256) void k_attn2(const float* __restrict__ qkv,
    ushort* __restrict__ aoh, ushort* __restrict__ aol) {
  __shared__ float Qs[QB][64];
  __shared__ float KVs[128][68];
  __shared__ float sc[QB][516];
  __shared__ float red[256];
  __shared__ float mrow[QB], invr[QB];
  int qt = blockIdx.x, h = blockIdx.y, b = blockIdx.z;
  int tid = threadIdx.x;
  int q0 = qt * QB;
  const float* base = qkv + (size_t)(b * SQ) * (3 * DM);
  {
    int qi = tid >> 4, d4 = (tid & 15) * 4;
    *(float4*)&Qs[qi][d4] = *(const float4*)&base[(size_t)(q0 + qi) * (3 * DM) + h * HD + d4];
  }
  for (int kt = 0; kt < 4; ++kt) {
    __syncthreads();
    {
      int kk = tid >> 4, d4 = (tid & 15) * 4;
#pragma unroll
      for (int i = 0; i < 8; ++i)
        *(float4*)&KVs[kk + 16 * i][d4] =
            *(const float4*)&base[(size_t)(kt * 128 + kk + 16 * i) * (3 * DM) + DM + h * HD + d4];
    }
    __syncthreads();
    int q2 = tid >> 5, k4 = tid & 31;
    float a0[4] = {}, a1[4] = {};
#pragma unroll
    for (int i = 0; i < 16; ++i) {
      float4 qa = *(float4*)&Qs[2 * q2][4 * i];
      float4 qb = *(float4*)&Qs[2 * q2 + 1][4 * i];
#pragma unroll
      for (int j = 0; j < 4; ++j) {
        float4 kv = *(float4*)&KVs[k4 + 32 * j][4 * i];
        a0[j] += qa.x * kv.x + qa.y * kv.y + qa.z * kv.z + qa.w * kv.w;
        a1[j] += qb.x * kv.x + qb.y * kv.y + qb.z * kv.z + qb.w * kv.w;
      }
    }
#pragma unroll
    for (int j = 0; j < 4; ++j) {
      sc[2 * q2][kt * 128 + 32 * j + k4] = a0[j] * 0.125f;
      sc[2 * q2 + 1][kt * 128 + 32 * j + k4] = a1[j] * 0.125f;
    }
  }
  __syncthreads();
  int row = tid & 15, seg = tid >> 4;
  float m = -1e30f;
  for (int i = 0; i < 32; ++i) m = fmaxf(m, sc[row][seg + 16 * i]);
  red[tid] = m; __syncthreads();
  if (tid < QB) {
    float mm = red[tid];
#pragma unroll
    for (int j = 1; j < 16; ++j) mm = fmaxf(mm, red[tid + 16 * j]);
    mrow[tid] = mm;
  }
  __syncthreads();
  m = mrow[row];
  float s = 0.f;
  for (int i = 0; i < 32; ++i) {
    int c = seg + 16 * i;
    float e = expf(sc[row][c] - m);
    sc[row][c] = e; s += e;
  }
  red[tid] = s; __syncthreads();
  if (tid < QB) {
    float ss = red[tid];
#pragma unroll
    for (int j = 1; j < 16; ++j) ss += red[tid + 16 * j];
    invr[tid] = 1.0f / ss;
  }
  float4 o = {0.f, 0.f, 0.f, 0.f};
  int q = tid >> 4, d4 = (tid & 15) * 4;
  for (int vt = 0; vt < 4; ++vt) {
    __syncthreads();
    {
      int kk = tid >> 4, dd = (tid & 15) * 4;
#pragma unroll
      for (int i = 0; i < 8; ++i)
        *(float4*)&KVs[kk + 16 * i][dd] =
            *(const float4*)&base[(size_t)(vt * 128 + kk + 16 * i) * (3 * DM) + 2 * DM + h * HD + dd];
    }
    __syncthreads();
    for (int kk = 0; kk < 128; ++kk) {
      float w = sc[q][vt * 128 + kk];
      float4 v = *(float4*)&KVs[kk][d4];
      o.x += w * v.x; o.y += w * v.y; o.z += w * v.z; o.w += w * v.w;
    }
  }
  float iv = invr[q];
  size_t ob = (size_t)(b * SQ + q0 + q) * DM + h * HD + d4;
  float ov[4] = {o.x * iv, o.y * iv, o.z * iv, o.w * iv};
#pragma unroll
  for (int j = 0; j < 4; ++j) {
    ushort hh = f2b(ov[j]);
    aoh[ob + j] = hh;
    aol[ob + j] = f2b(ov[j] - b2f(hh));
  }
}

// ================= split-precision rmsnorm (+ optional counts zeroing) =================
__global__ __launch_bounds__(256) void k_rmsnorm_sb(const float* __restrict__ x,
    const float* __restrict__ w, float* __restrict__ y,
    ushort* __restrict__ yh, ushort* __restrict__ yl, int* __restrict__ zc) {
  __shared__ float red[256];
  int t = blockIdx.x, tid = threadIdx.x;
  if (zc && t == 0 && tid < NE) zc[tid] = 0;
  float ss = 0.f;
  for (int d = tid; d < DM; d += 256) { float v = x[t * DM + d]; ss += v * v; }
  red[tid] = ss; __syncthreads();
  for (int s = 128; s > 0; s >>= 1) { if (tid < s) red[tid] += red[tid + s]; __syncthreads(); }
  float inv = 1.0f / sqrtf(red[0] / (float)DM + REPS);
  for (int d = tid; d < DM; d += 256) {
    float v = w[d] * x[t * DM + d] * inv;
    ushort h = f2b(v);
    y[t * DM + d] = v;
    yh[t * DM + d] = h;
    yl[t * DM + d] = f2b(v - b2f(h));
  }
}

__global__ __launch_bounds__(256) void k_rmsnorm_b(const float* __restrict__ x,
    const float* __restrict__ w, ushort* __restrict__ y) {
  __shared__ float red[256];
  int t = blockIdx.x, tid = threadIdx.x;
  float ss = 0.f;
  for (int d = tid; d < DM; d += 256) { float v = x[t * DM + d]; ss += v * v; }
  red[tid] = ss; __syncthreads();
  for (int s = 128; s > 0; s >>= 1) { if (tid < s) red[tid] += red[tid + s]; __syncthreads(); }
  float inv = 1.0f / sqrtf(red[0] / (float)DM + REPS);
  for (int d = tid; d < DM; d += 256)
    y[t * DM + d] = f2b(w[d] * x[t * DM + d] * inv);
}

// ================= pipelined GEMM (r14-verified core; offs computed inline) =================
#define EPI_RES  1
#define EPI_F32  2
#define EPI_GU   3
#define EPI_DOWN 4
#define MODE_B   0
#define MODE_QKV 1
#define MODE_GU  2

template<int BM, int BN, int MODE, int EPI, int RM, int NBX, int PREC, int DEC>
__global__ __launch_bounds__(256) void k_gmm2(
    const ushort* __restrict__ Ah, const ushort* __restrict__ Al,
    const float* __restrict__ B0, const float* __restrict__ B1, const float* __restrict__ B2,
    long long bstride, ushort* __restrict__ Ch, ushort* __restrict__ Cl,
    float* __restrict__ Cf,
    int M, int K, int ldb, int ldc,
    const int* __restrict__ slot, const int* __restrict__ counts) {
  constexpr int NEg  = (RM == 0) ? 1 : NE;
  constexpr int P    = NBX * NEg;
  constexpr int Ppad = ((P + 7) / 8) * 8;
  constexpr int MB   = TT / BM;
  int id = blockIdx.x;
  int m, pp;
  if (DEC == 0) { m = id / Ppad; pp = id % Ppad; }
  else          { m = id % MB;   pp = id / MB;   }
  if (pp >= P) return;
  int e = pp / NBX;
  int x = pp % NBX;

  int cnt = (RM == 0) ? M : counts[e];
  int m0 = m * BM;
  if (m0 >= cnt) return;
  int n0 = x * BN;
  int off = 0;
  if (RM != 0) {
#pragma unroll
    for (int i = 0; i < NE; ++i) if (i < e) off += counts[i];
  }

  constexpr int WM = (BM == 128) ? 64 : ((BN == 128) ? 64 : 32);
  constexpr int WN = (BM == 128) ? 64 : 32;
  constexpr int MI = WM / 16, NI = WN / 16;

  __shared__ __align__(16) ushort Ahs[BM * 40];
  __shared__ __align__(16) ushort Als[(PREC == 2) ? BM * 40 : 16];
  __shared__ __align__(16) ushort Bhs[BN * 40];
  __shared__ __align__(16) ushort Bls[(PREC == 2) ? BN * 40 : 16];

  int tid = threadIdx.x;
  int wave = tid >> 6, lane = tid & 63;
  int wr, wc;
  if (BM == 128)      { wr = wave >> 1; wc = wave & 1; }
  else if (BN == 128) { wr = 0;         wc = wave;     }
  else                { wr = wave >> 1; wc = wave & 1; }
  int moff;
  if (BM == 64 && BN == 128) moff = 0; else moff = wr * ((BM == 128) ? 64 : 32);
  int noff = wc * WN;

  int arA = tid >> 2, kcA = tid & 3;
  int ar1 = tid >> 2, ar2 = ar1 + 64;
  size_t aoff1 = 0, aoff2 = 0;
  if (BM == 64) {
    int rowi;
    if (RM == 0)      rowi = m0 + arA;
    else if (RM == 1) rowi = slot[e * TT + min(m0 + arA, cnt - 1)];
    else              rowi = off + min(m0 + arA, cnt - 1);
    aoff1 = (size_t)rowi * K;
  } else {
    if (RM == 0) {
      aoff1 = (size_t)(m0 + ar1) * K;
      aoff2 = (size_t)(m0 + ar2) * K;
    } else if (RM == 1) {
      aoff1 = (size_t)slot[e * TT + min(m0 + ar1, cnt - 1)] * K;
      aoff2 = (size_t)slot[e * TT + min(m0 + ar2, cnt - 1)] * K;
    } else {
      aoff1 = (size_t)(off + min(m0 + ar1, cnt - 1)) * K;
      aoff2 = (size_t)(off + min(m0 + ar2, cnt - 1)) * K;
    }
  }

  int rB = tid & 63, ko = tid >> 6;
  auto bcol = [&](int r) -> const float* {
    if (MODE == MODE_QKV) {
      int mat = x / (NBX / 3);
      const float* Bm = (mat == 0) ? B0 : ((mat == 1) ? B1 : B2);
      return Bm + (x % (NBX / 3)) * BN + r;
    } else if (MODE == MODE_GU) {
      const float* Bg = B0 + (size_t)e * bstride;
      const float* Bu = B1 + (size_t)e * bstride;
      return ((((r) >> 4) & 1) ? Bu : Bg) + x * (BN / 2) + ((((r) >> 5) << 4) | ((r) & 15));
    }
    return B0 + (size_t)e * bstride + n0 + r;
  };
  const float* bs0 = bcol(rB);
  const float* bs1 = (BN == 128) ? bcol(rB + 64) : nullptr;

  s16x8 rah1, rah2, ral1, ral2;
  float vb0[8], vb1[8];

  auto loadA = [&](int kk) {
    if (BM == 64) {
      rah1 = *(const s16x8*)(Ah + aoff1 + kk + kcA * 8);
      if (PREC == 2) ral1 = *(const s16x8*)(Al + aoff1 + kk + kcA * 8);
    } else {
      rah1 = *(const s16x8*)(Ah + aoff1 + kk + kcA * 8);
      rah2 = *(const s16x8*)(Ah + aoff2 + kk + kcA * 8);
      if (PREC == 2) {
        ral1 = *(const s16x8*)(Al + aoff1 + kk + kcA * 8);
        ral2 = *(const s16x8*)(Al + aoff2 + kk + kcA * 8);
      }
    }
  };
  auto loadB = [&](int kk) {
#pragma unroll
    for (int i = 0; i < 8; ++i)
      vb0[i] = bs0[(size_t)(kk + ko * 8 + i) * ldb];
    if (BN == 128) {
#pragma unroll
      for (int i = 0; i < 8; ++i)
        vb1[i] = bs1[(size_t)(kk + ko * 8 + i) * ldb];
    }
  };
  auto storeLDS = [&]() {
    if (BM == 64) {
      *(s16x8*)&Ahs[arA * 40 + kcA * 8] = rah1;
      if (PREC == 2) *(s16x8*)&Als[arA * 40 + kcA * 8] = ral1;
    } else {
      *(s16x8*)&Ahs[ar1 * 40 + kcA * 8] = rah1;
      *(s16x8*)&Ahs[ar2 * 40 + kcA * 8] = rah2;
      if (PREC == 2) {
        *(s16x8*)&Als[ar1 * 40 + kcA * 8] = ral1;
        *(s16x8*)&Als[ar2 * 40 + kcA * 8] = ral2;
      }
    }
    s16x8 h0, l0;
#pragma unroll
    for (int i = 0; i < 8; ++i) {
      ushort h = f2b(vb0[i]);
      h0[i] = (short)h;
      if (PREC == 2) l0[i] = (short)f2b(vb0[i] - b2f(h));
    }
    *(s16x8*)&Bhs[rB * 40 + ko * 8] = h0;
    if (PREC == 2) *(s16x8*)&Bls[rB * 40 + ko * 8] = l0;
    if (BN == 128) {
      s16x8 h1, l1;
#pragma unroll
      for (int i = 0; i < 8; ++i) {
        ushort h = f2b(vb1[i]);
        h1[i] = (short)h;
        if (PREC == 2) l1[i] = (short)f2b(vb1[i] - b2f(h));
      }
      *(s16x8*)&Bhs[(rB + 64) * 40 + ko * 8] = h1;
      if (PREC == 2) *(s16x8*)&Bls[(rB + 64) * 40 + ko * 8] = l1;
    }
  };

  f32x4 zr = {0.f, 0.f, 0.f, 0.f};
  f32x4 acc[MI][NI];
#pragma unroll
  for (int i = 0; i < MI; ++i)
#pragma unroll
    for (int j = 0; j < NI; ++j) acc[i][j] = zr;

  int rl = lane & 15, g = lane >> 4;
  loadA(0); loadB(0);
  for (int k0 = 0; k0 < K; k0 += 32) {
    __syncthreads();
    storeLDS();
    __syncthreads();
    if (k0 + 32 < K) { loadA(k0 + 32); loadB(k0 + 32); }
#pragma unroll
    for (int mi = 0; mi < MI; ++mi) {
      int ra = (moff + mi * 16 + rl) * 40 + g * 8;
      s16x8 avh = *(const s16x8*)&Ahs[ra];
      s16x8 avl;
      if (PREC == 2) avl = *(const s16x8*)&Als[ra];
#pragma unroll
      for (int ni = 0; ni < NI; ++ni) {
        int rb = (noff + ni * 16 + rl) * 40 + g * 8;
        s16x8 bvh = *(const s16x8*)&Bhs[rb];
        f32x4 a = acc[mi][ni];
        if (PREC == 2) {
          s16x8 bvl = *(const s16x8*)&Bls[rb];
          a = __builtin_amdgcn_mfma_f32_16x16x32_bf16(avl, bvh, a, 0, 0, 0);
          a = __builtin_amdgcn_mfma_f32_16x16x32_bf16(avh, bvl, a, 0, 0, 0);
        }
        a = __builtin_amdgcn_mfma_f32_16x16x32_bf16(avh, bvh, a, 0, 0, 0);
        acc[mi][ni] = a;
      }
    }
  }

  int rg4 = (lane >> 4) * 4;
#pragma unroll
  for (int mi = 0; mi < MI; ++mi) {
#pragma unroll
    for (int rg = 0; rg < 4; ++rg) {
      int rloc = m0 + moff + mi * 16 + rg4 + rg;
      if ((EPI == EPI_GU || EPI == EPI_DOWN) && rloc >= cnt) continue;
      if (EPI == EPI_GU) {
        float gv = acc[mi][0][rg], uv = acc[mi][1][rg];
        float hv = gv / (1.f + __expf(-gv)) * uv;
        int fq = (n0 + noff) >> 5;
        size_t ix = (size_t)(off + rloc) * ldc + fq * 16 + rl;
        ushort h = f2b(hv);
        Ch[ix] = h;
        Cl[ix] = f2b(hv - b2f(h));
      } else if (EPI == EPI_RES) {
#pragma unroll
        for (int ni = 0; ni < NI; ++ni) {
          size_t ix = (size_t)rloc * ldc + n0 + noff + ni * 16 + rl;
          Cf[ix] += acc[mi][ni][rg];
        }
      } else if (EPI == EPI_F32) {
#pragma unroll
        for (int ni = 0; ni < NI; ++ni)
          Cf[(size_t)rloc * ldc + n0 + noff + ni * 16 + rl] = acc[mi][ni][rg];
      } else {  // EPI_DOWN
#pragma unroll
        for (int ni = 0; ni < NI; ++ni)
          Cf[(size_t)(off + rloc) * ldc + n0 + noff + ni * 16 + rl] = acc[mi][ni][rg];
      }
    }
  }
}

extern "C" void kernel_launch(void* const* d_in, const int* in_sizes, int n_in,
                              void* d_out, int out_size, void* d_ws, size_t ws_size,
                              hipStream_t stream) {
  (void)in_sizes; (void)n_in; (void)out_size; (void)ws_size;
  const int*   ids = (const int*)d_in[0];
  const float* tok = (const float*)d_in[1];
  const float* pos = (const float*)d_in[2];
  const float* wq  = (const float*)d_in[3];
  const float* wk  = (const float*)d_in[4];
  const float* wv  = (const float*)d_in[5];
  const float* wo  = (const float*)d_in[6];
  const float* n1w = (const float*)d_in[7];
  const float* n2w = (const float*)d_in[8];
  const float* rw  = (const float*)d_in[9];
  const float* gw  = (const float*)d_in[10];
  const float* uw  = (const float*)d_in[11];
  const float* dw  = (const float*)d_in[12];
  const float* fnw = (const float*)d_in[13];
  const float* lmw = (const float*)d_in[14];
  float* out = (float*)d_out;

  char* p = (char*)d_ws;
  auto alloc = [&](size_t bytes) { char* r = p; p += (bytes + 255) & ~(size_t)255; return r; };
  float*  x    = (float*)alloc((size_t)TT * DM * 4);
  float*  xn   = (float*)alloc((size_t)TT * DM * 4);
  ushort* xh   = (ushort*)alloc((size_t)TT * DM * 2);
  ushort* xl   = (ushort*)alloc((size_t)TT * DM * 2);
  float*  qkv  = (float*)alloc((size_t)TT * 3 * DM * 4);
  ushort* aoh  = (ushort*)alloc((size_t)TT * DM * 2);
  ushort* aol  = (ushort*)alloc((size_t)TT * DM * 2);
  ushort* Hh   = (ushort*)alloc((size_t)2 * TT * FFD * 2);
  ushort* Hl   = (ushort*)alloc((size_t)2 * TT * FFD * 2);
  float*  eo   = (float*)alloc((size_t)2 * TT * DM * 4);
  float*  topw = (float*)alloc((size_t)2 * TT * 4);
  int* topi    = (int*)alloc((size_t)2 * TT * 4);
  int* posb    = (int*)alloc((size_t)2 * TT * 4);
  int* slot    = (int*)alloc((size_t)NE * TT * 4);
  int* counts  = (int*)alloc(256);
  ushort* xnb  = (ushort*)alloc((size_t)TT * DM * 2);

  k_embed<<<TT, 256, 0, stream>>>(ids, tok, pos, x);
  for (int l = 0; l < NL; ++l) {
    // attention
    k_rmsnorm_sb<<<TT, 256, 0, stream>>>(x, n1w + l * DM, xn, xh, xl, nullptr);
    k_gmm2<64, 64, MODE_QKV, EPI_F32, 0, 36, 2, 0><<<16 * 40, 256, 0, stream>>>(
        xh, xl, wq + (size_t)l * DM * DM, wk + (size_t)l * DM * DM, wv + (size_t)l * DM * DM,
        0, nullptr, nullptr, qkv, TT, DM, DM, 3 * DM, nullptr, nullptr);
    k_attn2<<<dim3(SQ / QB, NH, NB), 256, 0, stream>>>(qkv, aoh, aol);
    k_gmm2<64, 64, MODE_B, EPI_RES, 0, 12, 2, 0><<<16 * 16, 256, 0, stream>>>(
        aoh, aol, wo + (size_t)l * DM * DM, nullptr, nullptr,
        0, nullptr, nullptr, x, TT, DM, DM, DM, nullptr, nullptr);

    // MoE (counts zeroed by rmsnorm_sb block 0)
    k_rmsnorm_sb<<<TT, 256, 0, stream>>>(x, n2w + l * DM, xn, xh, xl, counts);
    k_router<<<TT, 64, 0, stream>>>(xn, rw + (size_t)l * DM * NE, topi, topw, posb, slot, counts);
    k_gmm2<64, 128, MODE_GU, EPI_GU, 1, 32, 2, 0><<<16 * 256, 256, 0, stream>>>(
        xh, xl, gw + (size_t)l * NE * DM * FFD, uw + (size_t)l * NE * DM * FFD, nullptr,
        (long long)DM * FFD, Hh, Hl, nullptr, TT, DM, FFD, FFD, slot, counts);
    k_gmm2<64, 64, MODE_B, EPI_DOWN, 2, 12, 2, 0><<<16 * 96, 256, 0, stream>>>(
        Hh, Hl, dw + (size_t)l * NE * FFD * DM, nullptr, nullptr,
        (long long)FFD * DM, nullptr, nullptr, eo, TT, FFD, DM, DM, nullptr, counts);
    k_combine<<<TT, 256, 0, stream>>>(eo, topi, topw, posb, counts, x);
  }

  // LM head: single launch, direct fp32 B, bf16-hi precision, m-inner decode for B-panel L2 reuse
  k_rmsnorm_b<<<TT, 256, 0, stream>>>(x, fnw, xnb);
  k_gmm2<64, 128, MODE_B, EPI_F32, 0, 250, 1, 1><<<16 * 256, 256, 0, stream>>>(
      xnb, nullptr, lmw, nullptr, nullptr,
      0, nullptr, nullptr, out, TT, DM, NV, NV, nullptr, nullptr);
}

// Round 16
// 1434.062 us; speedup vs baseline: 4.6944x; 1.0361x over previous
//
#include <hip/hip_runtime.h>
#include <math.h>

#define TT   1024
#define DM   768
#define NH   12
#define HD   64
#define FFD  2048
#define NE   8
#define SQ   512
#define NB   2
#define NL   4
#define NV   32000
#define REPS 1e-6f
#define QB   16

typedef float f32x4 __attribute__((ext_vector_type(4)));
typedef short s16x8 __attribute__((ext_vector_type(8)));

__device__ __forceinline__ float b2f(ushort u) {
  return __uint_as_float(((unsigned)u) << 16);
}
__device__ __forceinline__ ushort f2b(float f) {
  unsigned i = __float_as_uint(f);
  return (ushort)((i + 0x7FFFu + ((i >> 16) & 1u)) >> 16);
}

// ================= small kernels (verified) =================
__global__ __launch_bounds__(256) void k_embed(const int* __restrict__ ids,
    const float* __restrict__ tok, const float* __restrict__ pos, float* __restrict__ x) {
  int t = blockIdx.x; int s = t % SQ; int id = ids[t];
  for (int d = threadIdx.x; d < DM; d += 256)
    x[t * DM + d] = tok[(size_t)id * DM + d] + pos[s * DM + d];
}

__global__ __launch_bounds__(64) void k_router(const float* __restrict__ xn,
    const float* __restrict__ rw, int* __restrict__ topi, float* __restrict__ topw,
    int* __restrict__ posb, int* __restrict__ slot, int* __restrict__ counts) {
  int t = blockIdx.x, l = threadIdx.x;
  float acc[NE] = {};
  for (int d = l; d < DM; d += 64) {
    float xv = xn[t * DM + d];
    const float* r = &rw[d * NE];
#pragma unroll
    for (int e = 0; e < NE; ++e) acc[e] += xv * r[e];
  }
#pragma unroll
  for (int off = 32; off > 0; off >>= 1)
#pragma unroll
    for (int e = 0; e < NE; ++e) acc[e] += __shfl_down(acc[e], off, 64);
  if (l == 0) {
    float mx = acc[0];
#pragma unroll
    for (int e = 1; e < NE; ++e) mx = fmaxf(mx, acc[e]);
    float p[NE], sum = 0.f;
#pragma unroll
    for (int e = 0; e < NE; ++e) { p[e] = expf(acc[e] - mx); sum += p[e]; }
#pragma unroll
    for (int e = 0; e < NE; ++e) p[e] /= sum;
    int i0 = 0;
    for (int e = 1; e < NE; ++e) if (p[e] > p[i0]) i0 = e;
    int i1 = (i0 == 0) ? 1 : 0;
    for (int e = 0; e < NE; ++e) if (e != i0 && p[e] > p[i1]) i1 = e;
    float w0 = p[i0], w1 = p[i1], inv = 1.f / (w0 + w1);
    w0 *= inv; w1 *= inv;
    int p0 = atomicAdd(&counts[i0], 1);
    int p1 = atomicAdd(&counts[i1], 1);
    topi[2 * t] = i0; topi[2 * t + 1] = i1;
    topw[2 * t] = w0; topw[2 * t + 1] = w1;
    posb[2 * t] = p0; posb[2 * t + 1] = p1;
    slot[i0 * TT + p0] = t; slot[i1 * TT + p1] = t;
  }
}

__global__ __launch_bounds__(256) void k_combine(const float* __restrict__ eo,
    const int* __restrict__ topi, const float* __restrict__ topw,
    const int* __restrict__ posb, const int* __restrict__ counts, float* __restrict__ x) {
  int t = blockIdx.x;
  int pre[NE]; int a = 0;
#pragma unroll
  for (int e = 0; e < NE; ++e) { pre[e] = a; a += counts[e]; }
  int r0 = pre[topi[2 * t]] + posb[2 * t];
  int r1 = pre[topi[2 * t + 1]] + posb[2 * t + 1];
  float w0 = topw[2 * t], w1 = topw[2 * t + 1];
  for (int d = threadIdx.x; d < DM; d += 256)
    x[t * DM + d] += w0 * eo[(size_t)r0 * DM + d] + w1 * eo[(size_t)r1 * DM + d];
}

// ================= tiled fp32 attention, split-output epilogue (r15-verified) =================
__global__ __launch_bounds__(256) void k_attn2(const float* __restrict__ qkv,
    ushort* __restrict__ aoh, ushort* __restrict__ aol) {
  __shared__ float Qs[QB][64];
  __shared__ float KVs[128][68];
  __shared__ float sc[QB][516];
  __shared__ float red[256];
  __shared__ float mrow[QB], invr[QB];
  int qt = blockIdx.x, h = blockIdx.y, b = blockIdx.z;
  int tid = threadIdx.x;
  int q0 = qt * QB;
  const float* base = qkv + (size_t)(b * SQ) * (3 * DM);
  {
    int qi = tid >> 4, d4 = (tid & 15) * 4;
    *(float4*)&Qs[qi][d4] = *(const float4*)&base[(size_t)(q0 + qi) * (3 * DM) + h * HD + d4];
  }
  for (int kt = 0; kt < 4; ++kt) {
    __syncthreads();
    {
      int kk = tid >> 4, d4 = (tid & 15) * 4;
#pragma unroll
      for (int i = 0; i < 8; ++i)
        *(float4*)&KVs[kk + 16 * i][d4] =
            *(const float4*)&base[(size_t)(kt * 128 + kk + 16 * i) * (3 * DM) + DM + h * HD + d4];
    }
    __syncthreads();
    int q2 = tid >> 5, k4 = tid & 31;
    float a0[4] = {}, a1[4] = {};
#pragma unroll
    for (int i = 0; i < 16; ++i) {
      float4 qa = *(float4*)&Qs[2 * q2][4 * i];
      float4 qb = *(float4*)&Qs[2 * q2 + 1][4 * i];
#pragma unroll
      for (int j = 0; j < 4; ++j) {
        float4 kv = *(float4*)&KVs[k4 + 32 * j][4 * i];
        a0[j] += qa.x * kv.x + qa.y * kv.y + qa.z * kv.z + qa.w * kv.w;
        a1[j] += qb.x * kv.x + qb.y * kv.y + qb.z * kv.z + qb.w * kv.w;
      }
    }
#pragma unroll
    for (int j = 0; j < 4; ++j) {
      sc[2 * q2][kt * 128 + 32 * j + k4] = a0[j] * 0.125f;
      sc[2 * q2 + 1][kt * 128 + 32 * j + k4] = a1[j] * 0.125f;
    }
  }
  __syncthreads();
  int row = tid & 15, seg = tid >> 4;
  float m = -1e30f;
  for (int i = 0; i < 32; ++i) m = fmaxf(m, sc[row][seg + 16 * i]);
  red[tid] = m; __syncthreads();
  if (tid < QB) {
    float mm = red[tid];
#pragma unroll
    for (int j = 1; j < 16; ++j) mm = fmaxf(mm, red[tid + 16 * j]);
    mrow[tid] = mm;
  }
  __syncthreads();
  m = mrow[row];
  float s = 0.f;
  for (int i = 0; i < 32; ++i) {
    int c = seg + 16 * i;
    float e = expf(sc[row][c] - m);
    sc[row][c] = e; s += e;
  }
  red[tid] = s; __syncthreads();
  if (tid < QB) {
    float ss = red[tid];
#pragma unroll
    for (int j = 1; j < 16; ++j) ss += red[tid + 16 * j];
    invr[tid] = 1.0f / ss;
  }
  float4 o = {0.f, 0.f, 0.f, 0.f};
  int q = tid >> 4, d4 = (tid & 15) * 4;
  for (int vt = 0; vt < 4; ++vt) {
    __syncthreads();
    {
      int kk = tid >> 4, dd = (tid & 15) * 4;
#pragma unroll
      for (int i = 0; i < 8; ++i)
        *(float4*)&KVs[kk + 16 * i][dd] =
            *(const float4*)&base[(size_t)(vt * 128 + kk + 16 * i) * (3 * DM) + 2 * DM + h * HD + dd];
    }
    __syncthreads();
    for (int kk = 0; kk < 128; ++kk) {
      float w = sc[q][vt * 128 + kk];
      float4 v = *(float4*)&KVs[kk][d4];
      o.x += w * v.x; o.y += w * v.y; o.z += w * v.z; o.w += w * v.w;
    }
  }
  float iv = invr[q];
  size_t ob = (size_t)(b * SQ + q0 + q) * DM + h * HD + d4;
  float ov[4] = {o.x * iv, o.y * iv, o.z * iv, o.w * iv};
#pragma unroll
  for (int j = 0; j < 4; ++j) {
    ushort hh = f2b(ov[j]);
    aoh[ob + j] = hh;
    aol[ob + j] = f2b(ov[j] - b2f(hh));
  }
}

// ================= split-precision rmsnorm (+ optional counts zeroing) =================
__global__ __launch_bounds__(256) void k_rmsnorm_sb(const float* __restrict__ x,
    const float* __restrict__ w, float* __restrict__ y,
    ushort* __restrict__ yh, ushort* __restrict__ yl, int* __restrict__ zc) {
  __shared__ float red[256];
  int t = blockIdx.x, tid = threadIdx.x;
  if (zc && t == 0 && tid < NE) zc[tid] = 0;
  float ss = 0.f;
  for (int d = tid; d < DM; d += 256) { float v = x[t * DM + d]; ss += v * v; }
  red[tid] = ss; __syncthreads();
  for (int s = 128; s > 0; s >>= 1) { if (tid < s) red[tid] += red[tid + s]; __syncthreads(); }
  float inv = 1.0f / sqrtf(red[0] / (float)DM + REPS);
  for (int d = tid; d < DM; d += 256) {
    float v = w[d] * x[t * DM + d] * inv;
    ushort h = f2b(v);
    y[t * DM + d] = v;
    yh[t * DM + d] = h;
    yl[t * DM + d] = f2b(v - b2f(h));
  }
}

__global__ __launch_bounds__(256) void k_rmsnorm_b(const float* __restrict__ x,
    const float* __restrict__ w, ushort* __restrict__ y) {
  __shared__ float red[256];
  int t = blockIdx.x, tid = threadIdx.x;
  float ss = 0.f;
  for (int d = tid; d < DM; d += 256) { float v = x[t * DM + d]; ss += v * v; }
  red[tid] = ss; __syncthreads();
  for (int s = 128; s > 0; s >>= 1) { if (tid < s) red[tid] += red[tid + s]; __syncthreads(); }
  float inv = 1.0f / sqrtf(red[0] / (float)DM + REPS);
  for (int d = tid; d < DM; d += 256)
    y[t * DM + d] = f2b(w[d] * x[t * DM + d] * inv);
}

// ================= pipelined GEMM (r15-verified core; DEC=2 = XCD-grouped panels) =================
#define EPI_RES  1
#define EPI_F32  2
#define EPI_GU   3
#define EPI_DOWN 4
#define MODE_B   0
#define MODE_QKV 1
#define MODE_GU  2

template<int BM, int BN, int MODE, int EPI, int RM, int NBX, int PREC, int DEC>
__global__ __launch_bounds__(256) void k_gmm2(
    const ushort* __restrict__ Ah, const ushort* __restrict__ Al,
    const float* __restrict__ B0, const float* __restrict__ B1, const float* __restrict__ B2,
    long long bstride, ushort* __restrict__ Ch, ushort* __restrict__ Cl,
    float* __restrict__ Cf,
    int M, int K, int ldb, int ldc,
    const int* __restrict__ slot, const int* __restrict__ counts) {
  constexpr int NEg  = (RM == 0) ? 1 : NE;
  constexpr int P    = NBX * NEg;
  constexpr int Ppad = ((P + 7) / 8) * 8;
  constexpr int MB   = TT / BM;
  int id = blockIdx.x;
  int m, pp;
  if (DEC == 0) { m = id / Ppad; pp = id % Ppad; }
  else {  // DEC==2: XCD-grouped: all m-blocks of a panel on one XCD, consecutively
    int xcd = id & 7, j = id >> 3;
    m = j % MB;
    pp = (j / MB) * 8 + xcd;
  }
  if (pp >= P) return;
  int e = pp / NBX;
  int x = pp % NBX;

  int cnt = (RM == 0) ? M : counts[e];
  int m0 = m * BM;
  if (m0 >= cnt) return;
  int n0 = x * BN;
  int off = 0;
  if (RM != 0) {
#pragma unroll
    for (int i = 0; i < NE; ++i) if (i < e) off += counts[i];
  }

  constexpr int WM = (BM == 128) ? 64 : ((BN == 128) ? 64 : 32);
  constexpr int WN = (BM == 128) ? 64 : 32;
  constexpr int MI = WM / 16, NI = WN / 16;

  __shared__ __align__(16) ushort Ahs[BM * 40];
  __shared__ __align__(16) ushort Als[(PREC == 2) ? BM * 40 : 16];
  __shared__ __align__(16) ushort Bhs[BN * 40];
  __shared__ __align__(16) ushort Bls[(PREC == 2) ? BN * 40 : 16];

  int tid = threadIdx.x;
  int wave = tid >> 6, lane = tid & 63;
  int wr, wc;
  if (BM == 128)      { wr = wave >> 1; wc = wave & 1; }
  else if (BN == 128) { wr = 0;         wc = wave;     }
  else                { wr = wave >> 1; wc = wave & 1; }
  int moff;
  if (BM == 64 && BN == 128) moff = 0; else moff = wr * ((BM == 128) ? 64 : 32);
  int noff = wc * WN;

  int arA = tid >> 2, kcA = tid & 3;
  int ar1 = tid >> 2, ar2 = ar1 + 64;
  size_t aoff1 = 0, aoff2 = 0;
  if (BM == 64) {
    int rowi;
    if (RM == 0)      rowi = m0 + arA;
    else if (RM == 1) rowi = slot[e * TT + min(m0 + arA, cnt - 1)];
    else              rowi = off + min(m0 + arA, cnt - 1);
    aoff1 = (size_t)rowi * K;
  } else {
    if (RM == 0) {
      aoff1 = (size_t)(m0 + ar1) * K;
      aoff2 = (size_t)(m0 + ar2) * K;
    } else if (RM == 1) {
      aoff1 = (size_t)slot[e * TT + min(m0 + ar1, cnt - 1)] * K;
      aoff2 = (size_t)slot[e * TT + min(m0 + ar2, cnt - 1)] * K;
    } else {
      aoff1 = (size_t)(off + min(m0 + ar1, cnt - 1)) * K;
      aoff2 = (size_t)(off + min(m0 + ar2, cnt - 1)) * K;
    }
  }

  int rB = tid & 63, ko = tid >> 6;
  auto bcol = [&](int r) -> const float* {
    if (MODE == MODE_QKV) {
      int mat = x / (NBX / 3);
      const float* Bm = (mat == 0) ? B0 : ((mat == 1) ? B1 : B2);
      return Bm + (x % (NBX / 3)) * BN + r;
    } else if (MODE == MODE_GU) {
      const float* Bg = B0 + (size_t)e * bstride;
      const float* Bu = B1 + (size_t)e * bstride;
      return ((((r) >> 4) & 1) ? Bu : Bg) + x * (BN / 2) + ((((r) >> 5) << 4) | ((r) & 15));
    }
    return B0 + (size_t)e * bstride + n0 + r;
  };
  const float* bs0 = bcol(rB);
  const float* bs1 = (BN == 128) ? bcol(rB + 64) : nullptr;

  s16x8 rah1, rah2, ral1, ral2;
  float vb0[8], vb1[8];

  auto loadA = [&](int kk) {
    if (BM == 64) {
      rah1 = *(const s16x8*)(Ah + aoff1 + kk + kcA * 8);
      if (PREC == 2) ral1 = *(const s16x8*)(Al + aoff1 + kk + kcA * 8);
    } else {
      rah1 = *(const s16x8*)(Ah + aoff1 + kk + kcA * 8);
      rah2 = *(const s16x8*)(Ah + aoff2 + kk + kcA * 8);
      if (PREC == 2) {
        ral1 = *(const s16x8*)(Al + aoff1 + kk + kcA * 8);
        ral2 = *(const s16x8*)(Al + aoff2 + kk + kcA * 8);
      }
    }
  };
  auto loadB = [&](int kk) {
#pragma unroll
    for (int i = 0; i < 8; ++i)
      vb0[i] = bs0[(size_t)(kk + ko * 8 + i) * ldb];
    if (BN == 128) {
#pragma unroll
      for (int i = 0; i < 8; ++i)
        vb1[i] = bs1[(size_t)(kk + ko * 8 + i) * ldb];
    }
  };
  auto storeLDS = [&]() {
    if (BM == 64) {
      *(s16x8*)&Ahs[arA * 40 + kcA * 8] = rah1;
      if (PREC == 2) *(s16x8*)&Als[arA * 40 + kcA * 8] = ral1;
    } else {
      *(s16x8*)&Ahs[ar1 * 40 + kcA * 8] = rah1;
      *(s16x8*)&Ahs[ar2 * 40 + kcA * 8] = rah2;
      if (PREC == 2) {
        *(s16x8*)&Als[ar1 * 40 + kcA * 8] = ral1;
        *(s16x8*)&Als[ar2 * 40 + kcA * 8] = ral2;
      }
    }
    s16x8 h0, l0;
#pragma unroll
    for (int i = 0; i < 8; ++i) {
      ushort h = f2b(vb0[i]);
      h0[i] = (short)h;
      if (PREC == 2) l0[i] = (short)f2b(vb0[i] - b2f(h));
    }
    *(s16x8*)&Bhs[rB * 40 + ko * 8] = h0;
    if (PREC == 2) *(s16x8*)&Bls[rB * 40 + ko * 8] = l0;
    if (BN == 128) {
      s16x8 h1, l1;
#pragma unroll
      for (int i = 0; i < 8; ++i) {
        ushort h = f2b(vb1[i]);
        h1[i] = (short)h;
        if (PREC == 2) l1[i] = (short)f2b(vb1[i] - b2f(h));
      }
      *(s16x8*)&Bhs[(rB + 64) * 40 + ko * 8] = h1;
      if (PREC == 2) *(s16x8*)&Bls[(rB + 64) * 40 + ko * 8] = l1;
    }
  };

  f32x4 zr = {0.f, 0.f, 0.f, 0.f};
  f32x4 acc[MI][NI];
#pragma unroll
  for (int i = 0; i < MI; ++i)
#pragma unroll
    for (int j = 0; j < NI; ++j) acc[i][j] = zr;

  int rl = lane & 15, g = lane >> 4;
  loadA(0); loadB(0);
  for (int k0 = 0; k0 < K; k0 += 32) {
    __syncthreads();
    storeLDS();
    __syncthreads();
    if (k0 + 32 < K) { loadA(k0 + 32); loadB(k0 + 32); }
#pragma unroll
    for (int mi = 0; mi < MI; ++mi) {
      int ra = (moff + mi * 16 + rl) * 40 + g * 8;
      s16x8 avh = *(const s16x8*)&Ahs[ra];
      s16x8 avl;
      if (PREC == 2) avl = *(const s16x8*)&Als[ra];
#pragma unroll
      for (int ni = 0; ni < NI; ++ni) {
        int rb = (noff + ni * 16 + rl) * 40 + g * 8;
        s16x8 bvh = *(const s16x8*)&Bhs[rb];
        f32x4 a = acc[mi][ni];
        if (PREC == 2) {
          s16x8 bvl = *(const s16x8*)&Bls[rb];
          a = __builtin_amdgcn_mfma_f32_16x16x32_bf16(avl, bvh, a, 0, 0, 0);
          a = __builtin_amdgcn_mfma_f32_16x16x32_bf16(avh, bvl, a, 0, 0, 0);
        }
        a = __builtin_amdgcn_mfma_f32_16x16x32_bf16(avh, bvh, a, 0, 0, 0);
        acc[mi][ni] = a;
      }
    }
  }

  int rg4 = (lane >> 4) * 4;
#pragma unroll
  for (int mi = 0; mi < MI; ++mi) {
#pragma unroll
    for (int rg = 0; rg < 4; ++rg) {
      int rloc = m0 + moff + mi * 16 + rg4 + rg;
      if ((EPI == EPI_GU || EPI == EPI_DOWN) && rloc >= cnt) continue;
      if (EPI == EPI_GU) {
        float gv = acc[mi][0][rg], uv = acc[mi][1][rg];
        float hv = gv / (1.f + __expf(-gv)) * uv;
        int fq = (n0 + noff) >> 5;
        size_t ix = (size_t)(off + rloc) * ldc + fq * 16 + rl;
        ushort h = f2b(hv);
        Ch[ix] = h;
        if (PREC == 2) Cl[ix] = f2b(hv - b2f(h));
      } else if (EPI == EPI_RES) {
#pragma unroll
        for (int ni = 0; ni < NI; ++ni) {
          size_t ix = (size_t)rloc * ldc + n0 + noff + ni * 16 + rl;
          Cf[ix] += acc[mi][ni][rg];
        }
      } else if (EPI == EPI_F32) {
#pragma unroll
        for (int ni = 0; ni < NI; ++ni)
          Cf[(size_t)rloc * ldc + n0 + noff + ni * 16 + rl] = acc[mi][ni][rg];
      } else {  // EPI_DOWN
#pragma unroll
        for (int ni = 0; ni < NI; ++ni)
          Cf[(size_t)(off + rloc) * ldc + n0 + noff + ni * 16 + rl] = acc[mi][ni][rg];
      }
    }
  }
}

extern "C" void kernel_launch(void* const* d_in, const int* in_sizes, int n_in,
                              void* d_out, int out_size, void* d_ws, size_t ws_size,
                              hipStream_t stream) {
  (void)in_sizes; (void)n_in; (void)out_size; (void)ws_size;
  const int*   ids = (const int*)d_in[0];
  const float* tok = (const float*)d_in[1];
  const float* pos = (const float*)d_in[2];
  const float* wq  = (const float*)d_in[3];
  const float* wk  = (const float*)d_in[4];
  const float* wv  = (const float*)d_in[5];
  const float* wo  = (const float*)d_in[6];
  const float* n1w = (const float*)d_in[7];
  const float* n2w = (const float*)d_in[8];
  const float* rw  = (const float*)d_in[9];
  const float* gw  = (const float*)d_in[10];
  const float* uw  = (const float*)d_in[11];
  const float* dw  = (const float*)d_in[12];
  const float* fnw = (const float*)d_in[13];
  const float* lmw = (const float*)d_in[14];
  float* out = (float*)d_out;

  char* p = (char*)d_ws;
  auto alloc = [&](size_t bytes) { char* r = p; p += (bytes + 255) & ~(size_t)255; return r; };
  float*  x    = (float*)alloc((size_t)TT * DM * 4);
  float*  xn   = (float*)alloc((size_t)TT * DM * 4);
  ushort* xh   = (ushort*)alloc((size_t)TT * DM * 2);
  ushort* xl   = (ushort*)alloc((size_t)TT * DM * 2);
  float*  qkv  = (float*)alloc((size_t)TT * 3 * DM * 4);
  ushort* aoh  = (ushort*)alloc((size_t)TT * DM * 2);
  ushort* aol  = (ushort*)alloc((size_t)TT * DM * 2);
  ushort* Hh   = (ushort*)alloc((size_t)2 * TT * FFD * 2);
  ushort* Hl   = (ushort*)alloc((size_t)2 * TT * FFD * 2);
  float*  eo   = (float*)alloc((size_t)2 * TT * DM * 4);
  float*  topw = (float*)alloc((size_t)2 * TT * 4);
  int* topi    = (int*)alloc((size_t)2 * TT * 4);
  int* posb    = (int*)alloc((size_t)2 * TT * 4);
  int* slot    = (int*)alloc((size_t)NE * TT * 4);
  int* counts  = (int*)alloc(256);
  ushort* xnb  = (ushort*)alloc((size_t)TT * DM * 2);

  k_embed<<<TT, 256, 0, stream>>>(ids, tok, pos, x);
  for (int l = 0; l < NL; ++l) {
    // attention
    k_rmsnorm_sb<<<TT, 256, 0, stream>>>(x, n1w + l * DM, xn, xh, xl, nullptr);
    k_gmm2<64, 64, MODE_QKV, EPI_F32, 0, 36, 2, 0><<<16 * 40, 256, 0, stream>>>(
        xh, xl, wq + (size_t)l * DM * DM, wk + (size_t)l * DM * DM, wv + (size_t)l * DM * DM,
        0, nullptr, nullptr, qkv, TT, DM, DM, 3 * DM, nullptr, nullptr);
    k_attn2<<<dim3(SQ / QB, NH, NB), 256, 0, stream>>>(qkv, aoh, aol);
    k_gmm2<64, 64, MODE_B, EPI_RES, 0, 12, 2, 0><<<16 * 16, 256, 0, stream>>>(
        aoh, aol, wo + (size_t)l * DM * DM, nullptr, nullptr,
        0, nullptr, nullptr, x, TT, DM, DM, DM, nullptr, nullptr);

    // MoE (counts zeroed by rmsnorm_sb block 0)
    k_rmsnorm_sb<<<TT, 256, 0, stream>>>(x, n2w + l * DM, xn, xh, xl, counts);
    k_router<<<TT, 64, 0, stream>>>(xn, rw + (size_t)l * DM * NE, topi, topw, posb, slot, counts);
    if (l < NL - 1) {
      // upstream of a later router: full split precision
      k_gmm2<64, 128, MODE_GU, EPI_GU, 1, 32, 2, 0><<<16 * 256, 256, 0, stream>>>(
          xh, xl, gw + (size_t)l * NE * DM * FFD, uw + (size_t)l * NE * DM * FFD, nullptr,
          (long long)DM * FFD, Hh, Hl, nullptr, TT, DM, FFD, FFD, slot, counts);
      k_gmm2<64, 64, MODE_B, EPI_DOWN, 2, 12, 2, 0><<<16 * 96, 256, 0, stream>>>(
          Hh, Hl, dw + (size_t)l * NE * FFD * DM, nullptr, nullptr,
          (long long)FFD * DM, nullptr, nullptr, eo, TT, FFD, DM, DM, nullptr, counts);
    } else {
      // last layer: no router downstream -> plain bf16-hi (1 MFMA per k-step)
      k_gmm2<64, 128, MODE_GU, EPI_GU, 1, 32, 1, 0><<<16 * 256, 256, 0, stream>>>(
          xh, nullptr, gw + (size_t)l * NE * DM * FFD, uw + (size_t)l * NE * DM * FFD, nullptr,
          (long long)DM * FFD, Hh, nullptr, nullptr, TT, DM, FFD, FFD, slot, counts);
      k_gmm2<64, 64, MODE_B, EPI_DOWN, 2, 12, 1, 0><<<16 * 96, 256, 0, stream>>>(
          Hh, nullptr, dw + (size_t)l * NE * FFD * DM, nullptr, nullptr,
          (long long)FFD * DM, nullptr, nullptr, eo, TT, FFD, DM, DM, nullptr, counts);
    }
    k_combine<<<TT, 256, 0, stream>>>(eo, topi, topw, posb, counts, x);
  }

  // LM head: single launch, XCD-grouped panel decode (DEC=2)
  k_rmsnorm_b<<<TT, 256, 0, stream>>>(x, fnw, xnb);
  k_gmm2<64, 128, MODE_B, EPI_F32, 0, 250, 1, 2><<<16 * 256, 256, 0, stream>>>(
      xnb, nullptr, lmw, nullptr, nullptr,
      0, nullptr, nullptr, out, TT, DM, NV, NV, nullptr, nullptr);
}

// Round 17
// 1337.701 us; speedup vs baseline: 5.0325x; 1.0720x over previous
//
#include <hip/hip_runtime.h>
#include <math.h>

#define TT   1024
#define DM   768
#define NH   12
#define HD   64
#define FFD  2048
#define NE   8
#define SQ   512
#define NB   2
#define NL   4
#define NV   32000
#define REPS 1e-6f
#define QB   16

typedef float f32x4 __attribute__((ext_vector_type(4)));
typedef short s16x8 __attribute__((ext_vector_type(8)));

__device__ __forceinline__ float b2f(ushort u) {
  return __uint_as_float(((unsigned)u) << 16);
}
__device__ __forceinline__ ushort f2b(float f) {
  unsigned i = __float_as_uint(f);
  return (ushort)((i + 0x7FFFu + ((i >> 16) & 1u)) >> 16);
}
__device__ __forceinline__ ushort t2b(float f) {  // truncate: 1 VALU op
  return (ushort)(__float_as_uint(f) >> 16);
}

// ================= embed (+ zero all per-layer counts) =================
__global__ __launch_bounds__(256) void k_embed(const int* __restrict__ ids,
    const float* __restrict__ tok, const float* __restrict__ pos, float* __restrict__ x,
    int* __restrict__ counts4) {
  int t = blockIdx.x;
  if (t == 0 && threadIdx.x < NL * NE) counts4[threadIdx.x] = 0;
  int s = t % SQ; int id = ids[t];
  for (int d = threadIdx.x; d < DM; d += 256)
    x[t * DM + d] = tok[(size_t)id * DM + d] + pos[s * DM + d];
}

// ================= first-layer rmsnorm -> split =================
__global__ __launch_bounds__(256) void k_rmsnorm_sb(const float* __restrict__ x,
    const float* __restrict__ w, ushort* __restrict__ yh, ushort* __restrict__ yl) {
  __shared__ float red[256];
  int t = blockIdx.x, tid = threadIdx.x;
  float ss = 0.f;
  for (int d = tid; d < DM; d += 256) { float v = x[t * DM + d]; ss += v * v; }
  red[tid] = ss; __syncthreads();
  for (int s = 128; s > 0; s >>= 1) { if (tid < s) red[tid] += red[tid + s]; __syncthreads(); }
  float inv = 1.0f / sqrtf(red[0] / (float)DM + REPS);
  for (int d = tid; d < DM; d += 256) {
    float v = w[d] * x[t * DM + d] * inv;
    ushort h = f2b(v);
    yh[t * DM + d] = h;
    yl[t * DM + d] = f2b(v - b2f(h));
  }
}

// ================= fused MoE rmsnorm + router =================
__global__ __launch_bounds__(256) void k_rmsnorm_rt(const float* __restrict__ x,
    const float* __restrict__ nw, const float* __restrict__ rw,
    ushort* __restrict__ yh, ushort* __restrict__ yl,
    int* __restrict__ topi, float* __restrict__ topw,
    int* __restrict__ posb, int* __restrict__ slot, int* __restrict__ counts) {
  __shared__ float red[256];
  __shared__ float rw4[4][NE];
  int t = blockIdx.x, tid = threadIdx.x;
  float xs[3];
  float ss = 0.f;
#pragma unroll
  for (int i = 0; i < 3; ++i) {
    float v = x[t * DM + tid + 256 * i];
    xs[i] = v; ss += v * v;
  }
  red[tid] = ss; __syncthreads();
  for (int s = 128; s > 0; s >>= 1) { if (tid < s) red[tid] += red[tid + s]; __syncthreads(); }
  float inv = 1.0f / sqrtf(red[0] / (float)DM + REPS);
  float acc[NE] = {};
#pragma unroll
  for (int i = 0; i < 3; ++i) {
    int d = tid + 256 * i;
    float v = nw[d] * xs[i] * inv;
    ushort h = f2b(v);
    yh[t * DM + d] = h;
    yl[t * DM + d] = f2b(v - b2f(h));
    const float* r = &rw[d * NE];
#pragma unroll
    for (int e = 0; e < NE; ++e) acc[e] += v * r[e];
  }
#pragma unroll
  for (int off = 32; off > 0; off >>= 1)
#pragma unroll
    for (int e = 0; e < NE; ++e) acc[e] += __shfl_down(acc[e], off, 64);
  int wv = tid >> 6, ln = tid & 63;
  if (ln == 0)
#pragma unroll
    for (int e = 0; e < NE; ++e) rw4[wv][e] = acc[e];
  __syncthreads();
  if (tid == 0) {
    float lg[NE];
#pragma unroll
    for (int e = 0; e < NE; ++e) lg[e] = rw4[0][e] + rw4[1][e] + rw4[2][e] + rw4[3][e];
    int i0 = 0;
    for (int e = 1; e < NE; ++e) if (lg[e] > lg[i0]) i0 = e;
    int i1 = (i0 == 0) ? 1 : 0;
    for (int e = 0; e < NE; ++e) if (e != i0 && lg[e] > lg[i1]) i1 = e;
    float e1 = __expf(lg[i1] - lg[i0]);
    float w0 = 1.f / (1.f + e1), w1 = e1 / (1.f + e1);
    int p0 = atomicAdd(&counts[i0], 1);
    int p1 = atomicAdd(&counts[i1], 1);
    topi[2 * t] = i0; topi[2 * t + 1] = i1;
    topw[2 * t] = w0; topw[2 * t + 1] = w1;
    posb[2 * t] = p0; posb[2 * t + 1] = p1;
    slot[i0 * TT + p0] = t; slot[i1 * TT + p1] = t;
  }
}

// ================= fused combine + next norm =================
// FINAL=0: writes split (yh,yl) for next layer's QKV. FINAL=1: writes bf16 (yh) for LM head.
template<int FINAL>
__global__ __launch_bounds__(256) void k_combine_norm(const float* __restrict__ eo,
    const int* __restrict__ topi, const float* __restrict__ topw,
    const int* __restrict__ posb, const int* __restrict__ counts,
    float* __restrict__ x, const float* __restrict__ w,
    ushort* __restrict__ yh, ushort* __restrict__ yl) {
  __shared__ float red[256];
  int t = blockIdx.x, tid = threadIdx.x;
  int pre[NE]; int a = 0;
#pragma unroll
  for (int e = 0; e < NE; ++e) { pre[e] = a; a += counts[e]; }
  int r0 = pre[topi[2 * t]] + posb[2 * t];
  int r1 = pre[topi[2 * t + 1]] + posb[2 * t + 1];
  float w0 = topw[2 * t], w1 = topw[2 * t + 1];
  float nv[3];
  float ss = 0.f;
#pragma unroll
  for (int i = 0; i < 3; ++i) {
    int d = tid + 256 * i;
    float v = x[t * DM + d] + w0 * eo[(size_t)r0 * DM + d] + w1 * eo[(size_t)r1 * DM + d];
    x[t * DM + d] = v;
    nv[i] = v; ss += v * v;
  }
  red[tid] = ss; __syncthreads();
  for (int s = 128; s > 0; s >>= 1) { if (tid < s) red[tid] += red[tid + s]; __syncthreads(); }
  float inv = 1.0f / sqrtf(red[0] / (float)DM + REPS);
#pragma unroll
  for (int i = 0; i < 3; ++i) {
    int d = tid + 256 * i;
    float u = w[d] * nv[i] * inv;
    if (FINAL) {
      yh[t * DM + d] = f2b(u);
    } else {
      ushort h = f2b(u);
      yh[t * DM + d] = h;
      yl[t * DM + d] = f2b(u - b2f(h));
    }
  }
}

// ================= tiled fp32 attention, split-output epilogue (r15-verified) =================
__global__ __launch_bounds__(256) void k_attn2(const float* __restrict__ qkv,
    ushort* __restrict__ aoh, ushort* __restrict__ aol) {
  __shared__ float Qs[QB][64];
  __shared__ float KVs[128][68];
  __shared__ float sc[QB][516];
  __shared__ float red[256];
  __shared__ float mrow[QB], invr[QB];
  int qt = blockIdx.x, h = blockIdx.y, b = blockIdx.z;
  int tid = threadIdx.x;
  int q0 = qt * QB;
  const float* base = qkv + (size_t)(b * SQ) * (3 * DM);
  {
    int qi = tid >> 4, d4 = (tid & 15) * 4;
    *(float4*)&Qs[qi][d4] = *(const float4*)&base[(size_t)(q0 + qi) * (3 * DM) + h * HD + d4];
  }
  for (int kt = 0; kt < 4; ++kt) {
    __syncthreads();
    {
      int kk = tid >> 4, d4 = (tid & 15) * 4;
#pragma unroll
      for (int i = 0; i < 8; ++i)
        *(float4*)&KVs[kk + 16 * i][d4] =
            *(const float4*)&base[(size_t)(kt * 128 + kk + 16 * i) * (3 * DM) + DM + h * HD + d4];
    }
    __syncthreads();
    int q2 = tid >> 5, k4 = tid & 31;
    float a0[4] = {}, a1[4] = {};
#pragma unroll
    for (int i = 0; i < 16; ++i) {
      float4 qa = *(float4*)&Qs[2 * q2][4 * i];
      float4 qb = *(float4*)&Qs[2 * q2 + 1][4 * i];
#pragma unroll
      for (int j = 0; j < 4; ++j) {
        float4 kv = *(float4*)&KVs[k4 + 32 * j][4 * i];
        a0[j] += qa.x * kv.x + qa.y * kv.y + qa.z * kv.z + qa.w * kv.w;
        a1[j] += qb.x * kv.x + qb.y * kv.y + qb.z * kv.z + qb.w * kv.w;
      }
    }
#pragma unroll
    for (int j = 0; j < 4; ++j) {
      sc[2 * q2][kt * 128 + 32 * j + k4] = a0[j] * 0.125f;
      sc[2 * q2 + 1][kt * 128 + 32 * j + k4] = a1[j] * 0.125f;
    }
  }
  __syncthreads();
  int row = tid & 15, seg = tid >> 4;
  float m = -1e30f;
  for (int i = 0; i < 32; ++i) m = fmaxf(m, sc[row][seg + 16 * i]);
  red[tid] = m; __syncthreads();
  if (tid < QB) {
    float mm = red[tid];
#pragma unroll
    for (int j = 1; j < 16; ++j) mm = fmaxf(mm, red[tid + 16 * j]);
    mrow[tid] = mm;
  }
  __syncthreads();
  m = mrow[row];
  float s = 0.f;
  for (int i = 0; i < 32; ++i) {
    int c = seg + 16 * i;
    float e = expf(sc[row][c] - m);
    sc[row][c] = e; s += e;
  }
  red[tid] = s; __syncthreads();
  if (tid < QB) {
    float ss = red[tid];
#pragma unroll
    for (int j = 1; j < 16; ++j) ss += red[tid + 16 * j];
    invr[tid] = 1.0f / ss;
  }
  float4 o = {0.f, 0.f, 0.f, 0.f};
  int q = tid >> 4, d4 = (tid & 15) * 4;
  for (int vt = 0; vt < 4; ++vt) {
    __syncthreads();
    {
      int kk = tid >> 4, dd = (tid & 15) * 4;
#pragma unroll
      for (int i = 0; i < 8; ++i)
        *(float4*)&KVs[kk + 16 * i][dd] =
            *(const float4*)&base[(size_t)(vt * 128 + kk + 16 * i) * (3 * DM) + 2 * DM + h * HD + dd];
    }
    __syncthreads();
    for (int kk = 0; kk < 128; ++kk) {
      float w = sc[q][vt * 128 + kk];
      float4 v = *(float4*)&KVs[kk][d4];
      o.x += w * v.x; o.y += w * v.y; o.z += w * v.z; o.w += w * v.w;
    }
  }
  float iv = invr[q];
  size_t ob = (size_t)(b * SQ + q0 + q) * DM + h * HD + d4;
  float ov[4] = {o.x * iv, o.y * iv, o.z * iv, o.w * iv};
#pragma unroll
  for (int j = 0; j < 4; ++j) {
    ushort hh = f2b(ov[j]);
    aoh[ob + j] = hh;
    aol[ob + j] = f2b(ov[j] - b2f(hh));
  }
}

// ================= pipelined GEMM (r16-verified; trunc-split staging) =================
#define EPI_RES  1
#define EPI_F32  2
#define EPI_GU   3
#define EPI_DOWN 4
#define MODE_B   0
#define MODE_QKV 1
#define MODE_GU  2

template<int BM, int BN, int MODE, int EPI, int RM, int NBX, int PREC, int DEC>
__global__ __launch_bounds__(256) void k_gmm2(
    const ushort* __restrict__ Ah, const ushort* __restrict__ Al,
    const float* __restrict__ B0, const float* __restrict__ B1, const float* __restrict__ B2,
    long long bstride, ushort* __restrict__ Ch, ushort* __restrict__ Cl,
    float* __restrict__ Cf,
    int M, int K, int ldb, int ldc,
    const int* __restrict__ slot, const int* __restrict__ counts) {
  constexpr int NEg  = (RM == 0) ? 1 : NE;
  constexpr int P    = NBX * NEg;
  constexpr int Ppad = ((P + 7) / 8) * 8;
  constexpr int MB   = TT / BM;
  int id = blockIdx.x;
  int m, pp;
  if (DEC == 0) { m = id / Ppad; pp = id % Ppad; }
  else {  // DEC==2: XCD-grouped panels
    int xcd = id & 7, j = id >> 3;
    m = j % MB;
    pp = (j / MB) * 8 + xcd;
  }
  if (pp >= P) return;
  int e = pp / NBX;
  int x = pp % NBX;

  int cnt = (RM == 0) ? M : counts[e];
  int m0 = m * BM;
  if (m0 >= cnt) return;
  int n0 = x * BN;
  int off = 0;
  if (RM != 0) {
#pragma unroll
    for (int i = 0; i < NE; ++i) if (i < e) off += counts[i];
  }

  constexpr int WM = (BM == 128) ? 64 : ((BN == 128) ? 64 : 32);
  constexpr int WN = (BM == 128) ? 64 : 32;
  constexpr int MI = WM / 16, NI = WN / 16;

  __shared__ __align__(16) ushort Ahs[BM * 40];
  __shared__ __align__(16) ushort Als[(PREC == 2) ? BM * 40 : 16];
  __shared__ __align__(16) ushort Bhs[BN * 40];
  __shared__ __align__(16) ushort Bls[(PREC == 2) ? BN * 40 : 16];

  int tid = threadIdx.x;
  int wave = tid >> 6, lane = tid & 63;
  int wr, wc;
  if (BM == 128)      { wr = wave >> 1; wc = wave & 1; }
  else if (BN == 128) { wr = 0;         wc = wave;     }
  else                { wr = wave >> 1; wc = wave & 1; }
  int moff;
  if (BM == 64 && BN == 128) moff = 0; else moff = wr * ((BM == 128) ? 64 : 32);
  int noff = wc * WN;

  int arA = tid >> 2, kcA = tid & 3;
  int ar1 = tid >> 2, ar2 = ar1 + 64;
  size_t aoff1 = 0, aoff2 = 0;
  if (BM == 64) {
    int rowi;
    if (RM == 0)      rowi = m0 + arA;
    else if (RM == 1) rowi = slot[e * TT + min(m0 + arA, cnt - 1)];
    else              rowi = off + min(m0 + arA, cnt - 1);
    aoff1 = (size_t)rowi * K;
  } else {
    if (RM == 0) {
      aoff1 = (size_t)(m0 + ar1) * K;
      aoff2 = (size_t)(m0 + ar2) * K;
    } else if (RM == 1) {
      aoff1 = (size_t)slot[e * TT + min(m0 + ar1, cnt - 1)] * K;
      aoff2 = (size_t)slot[e * TT + min(m0 + ar2, cnt - 1)] * K;
    } else {
      aoff1 = (size_t)(off + min(m0 + ar1, cnt - 1)) * K;
      aoff2 = (size_t)(off + min(m0 + ar2, cnt - 1)) * K;
    }
  }

  int rB = tid & 63, ko = tid >> 6;
  auto bcol = [&](int r) -> const float* {
    if (MODE == MODE_QKV) {
      int mat = x / (NBX / 3);
      const float* Bm = (mat == 0) ? B0 : ((mat == 1) ? B1 : B2);
      return Bm + (x % (NBX / 3)) * BN + r;
    } else if (MODE == MODE_GU) {
      const float* Bg = B0 + (size_t)e * bstride;
      const float* Bu = B1 + (size_t)e * bstride;
      return ((((r) >> 4) & 1) ? Bu : Bg) + x * (BN / 2) + ((((r) >> 5) << 4) | ((r) & 15));
    }
    return B0 + (size_t)e * bstride + n0 + r;
  };
  const float* bs0 = bcol(rB);
  const float* bs1 = (BN == 128) ? bcol(rB + 64) : nullptr;

  s16x8 rah1, rah2, ral1, ral2;
  float vb0[8], vb1[8];

  auto loadA = [&](int kk) {
    if (BM == 64) {
      rah1 = *(const s16x8*)(Ah + aoff1 + kk + kcA * 8);
      if (PREC == 2) ral1 = *(const s16x8*)(Al + aoff1 + kk + kcA * 8);
    } else {
      rah1 = *(const s16x8*)(Ah + aoff1 + kk + kcA * 8);
      rah2 = *(const s16x8*)(Ah + aoff2 + kk + kcA * 8);
      if (PREC == 2) {
        ral1 = *(const s16x8*)(Al + aoff1 + kk + kcA * 8);
        ral2 = *(const s16x8*)(Al + aoff2 + kk + kcA * 8);
      }
    }
  };
  auto loadB = [&](int kk) {
#pragma unroll
    for (int i = 0; i < 8; ++i)
      vb0[i] = bs0[(size_t)(kk + ko * 8 + i) * ldb];
    if (BN == 128) {
#pragma unroll
      for (int i = 0; i < 8; ++i)
        vb1[i] = bs1[(size_t)(kk + ko * 8 + i) * ldb];
    }
  };
  auto storeLDS = [&]() {
    if (BM == 64) {
      *(s16x8*)&Ahs[arA * 40 + kcA * 8] = rah1;
      if (PREC == 2) *(s16x8*)&Als[arA * 40 + kcA * 8] = ral1;
    } else {
      *(s16x8*)&Ahs[ar1 * 40 + kcA * 8] = rah1;
      *(s16x8*)&Ahs[ar2 * 40 + kcA * 8] = rah2;
      if (PREC == 2) {
        *(s16x8*)&Als[ar1 * 40 + kcA * 8] = ral1;
        *(s16x8*)&Als[ar2 * 40 + kcA * 8] = ral2;
      }
    }
    s16x8 h0, l0;
#pragma unroll
    for (int i = 0; i < 8; ++i) {
      ushort h = t2b(vb0[i]);
      h0[i] = (short)h;
      if (PREC == 2) l0[i] = (short)t2b(vb0[i] - b2f(h));
    }
    *(s16x8*)&Bhs[rB * 40 + ko * 8] = h0;
    if (PREC == 2) *(s16x8*)&Bls[rB * 40 + ko * 8] = l0;
    if (BN == 128) {
      s16x8 h1, l1;
#pragma unroll
      for (int i = 0; i < 8; ++i) {
        ushort h = t2b(vb1[i]);
        h1[i] = (short)h;
        if (PREC == 2) l1[i] = (short)t2b(vb1[i] - b2f(h));
      }
      *(s16x8*)&Bhs[(rB + 64) * 40 + ko * 8] = h1;
      if (PREC == 2) *(s16x8*)&Bls[(rB + 64) * 40 + ko * 8] = l1;
    }
  };

  f32x4 zr = {0.f, 0.f, 0.f, 0.f};
  f32x4 acc[MI][NI];
#pragma unroll
  for (int i = 0; i < MI; ++i)
#pragma unroll
    for (int j = 0; j < NI; ++j) acc[i][j] = zr;

  int rl = lane & 15, g = lane >> 4;
  loadA(0); loadB(0);
  for (int k0 = 0; k0 < K; k0 += 32) {
    __syncthreads();
    storeLDS();
    __syncthreads();
    if (k0 + 32 < K) { loadA(k0 + 32); loadB(k0 + 32); }
#pragma unroll
    for (int mi = 0; mi < MI; ++mi) {
      int ra = (moff + mi * 16 + rl) * 40 + g * 8;
      s16x8 avh = *(const s16x8*)&Ahs[ra];
      s16x8 avl;
      if (PREC == 2) avl = *(const s16x8*)&Als[ra];
#pragma unroll
      for (int ni = 0; ni < NI; ++ni) {
        int rb = (noff + ni * 16 + rl) * 40 + g * 8;
        s16x8 bvh = *(const s16x8*)&Bhs[rb];
        f32x4 a = acc[mi][ni];
        if (PREC == 2) {
          s16x8 bvl = *(const s16x8*)&Bls[rb];
          a = __builtin_amdgcn_mfma_f32_16x16x32_bf16(avl, bvh, a, 0, 0, 0);
          a = __builtin_amdgcn_mfma_f32_16x16x32_bf16(avh, bvl, a, 0, 0, 0);
        }
        a = __builtin_amdgcn_mfma_f32_16x16x32_bf16(avh, bvh, a, 0, 0, 0);
        acc[mi][ni] = a;
      }
    }
  }

  int rg4 = (lane >> 4) * 4;
#pragma unroll
  for (int mi = 0; mi < MI; ++mi) {
#pragma unroll
    for (int rg = 0; rg < 4; ++rg) {
      int rloc = m0 + moff + mi * 16 + rg4 + rg;
      if ((EPI == EPI_GU || EPI == EPI_DOWN) && rloc >= cnt) continue;
      if (EPI == EPI_GU) {
        float gv = acc[mi][0][rg], uv = acc[mi][1][rg];
        float hv = gv / (1.f + __expf(-gv)) * uv;
        int fq = (n0 + noff) >> 5;
        size_t ix = (size_t)(off + rloc) * ldc + fq * 16 + rl;
        ushort h = t2b(hv);
        Ch[ix] = h;
        if (PREC == 2) Cl[ix] = t2b(hv - b2f(h));
      } else if (EPI == EPI_RES) {
#pragma unroll
        for (int ni = 0; ni < NI; ++ni) {
          size_t ix = (size_t)rloc * ldc + n0 + noff + ni * 16 + rl;
          Cf[ix] += acc[mi][ni][rg];
        }
      } else if (EPI == EPI_F32) {
#pragma unroll
        for (int ni = 0; ni < NI; ++ni)
          Cf[(size_t)rloc * ldc + n0 + noff + ni * 16 + rl] = acc[mi][ni][rg];
      } else {  // EPI_DOWN
#pragma unroll
        for (int ni = 0; ni < NI; ++ni)
          Cf[(size_t)(off + rloc) * ldc + n0 + noff + ni * 16 + rl] = acc[mi][ni][rg];
      }
    }
  }
}

extern "C" void kernel_launch(void* const* d_in, const int* in_sizes, int n_in,
                              void* d_out, int out_size, void* d_ws, size_t ws_size,
                              hipStream_t stream) {
  (void)in_sizes; (void)n_in; (void)out_size; (void)ws_size;
  const int*   ids = (const int*)d_in[0];
  const float* tok = (const float*)d_in[1];
  const float* pos = (const float*)d_in[2];
  const float* wq  = (const float*)d_in[3];
  const float* wk  = (const float*)d_in[4];
  const float* wv  = (const float*)d_in[5];
  const float* wo  = (const float*)d_in[6];
  const float* n1w = (const float*)d_in[7];
  const float* n2w = (const float*)d_in[8];
  const float* rw  = (const float*)d_in[9];
  const float* gw  = (const float*)d_in[10];
  const float* uw  = (const float*)d_in[11];
  const float* dw  = (const float*)d_in[12];
  const float* fnw = (const float*)d_in[13];
  const float* lmw = (const float*)d_in[14];
  float* out = (float*)d_out;

  char* p = (char*)d_ws;
  auto alloc = [&](size_t bytes) { char* r = p; p += (bytes + 255) & ~(size_t)255; return r; };
  float*  x    = (float*)alloc((size_t)TT * DM * 4);
  ushort* xh   = (ushort*)alloc((size_t)TT * DM * 2);
  ushort* xl   = (ushort*)alloc((size_t)TT * DM * 2);
  float*  qkv  = (float*)alloc((size_t)TT * 3 * DM * 4);
  ushort* aoh  = (ushort*)alloc((size_t)TT * DM * 2);
  ushort* aol  = (ushort*)alloc((size_t)TT * DM * 2);
  ushort* Hh   = (ushort*)alloc((size_t)2 * TT * FFD * 2);
  ushort* Hl   = (ushort*)alloc((size_t)2 * TT * FFD * 2);
  float*  eo   = (float*)alloc((size_t)2 * TT * DM * 4);
  float*  topw = (float*)alloc((size_t)2 * TT * 4);
  int* topi    = (int*)alloc((size_t)2 * TT * 4);
  int* posb    = (int*)alloc((size_t)2 * TT * 4);
  int* slot    = (int*)alloc((size_t)NE * TT * 4);
  int* counts4 = (int*)alloc(256);
  ushort* xnb  = (ushort*)alloc((size_t)TT * DM * 2);

  k_embed<<<TT, 256, 0, stream>>>(ids, tok, pos, x, counts4);
  k_rmsnorm_sb<<<TT, 256, 0, stream>>>(x, n1w, xh, xl);
  for (int l = 0; l < NL; ++l) {
    int* counts = counts4 + NE * l;
    // attention
    k_gmm2<64, 64, MODE_QKV, EPI_F32, 0, 36, 2, 0><<<16 * 40, 256, 0, stream>>>(
        xh, xl, wq + (size_t)l * DM * DM, wk + (size_t)l * DM * DM, wv + (size_t)l * DM * DM,
        0, nullptr, nullptr, qkv, TT, DM, DM, 3 * DM, nullptr, nullptr);
    k_attn2<<<dim3(SQ / QB, NH, NB), 256, 0, stream>>>(qkv, aoh, aol);
    k_gmm2<64, 64, MODE_B, EPI_RES, 0, 12, 2, 0><<<16 * 16, 256, 0, stream>>>(
        aoh, aol, wo + (size_t)l * DM * DM, nullptr, nullptr,
        0, nullptr, nullptr, x, TT, DM, DM, DM, nullptr, nullptr);

    // MoE: fused norm+router, then expert GEMMs
    k_rmsnorm_rt<<<TT, 256, 0, stream>>>(x, n2w + l * DM, rw + (size_t)l * DM * NE,
                                         xh, xl, topi, topw, posb, slot, counts);
    if (l < NL - 1) {
      k_gmm2<64, 128, MODE_GU, EPI_GU, 1, 32, 2, 0><<<16 * 256, 256, 0, stream>>>(
          xh, xl, gw + (size_t)l * NE * DM * FFD, uw + (size_t)l * NE * DM * FFD, nullptr,
          (long long)DM * FFD, Hh, Hl, nullptr, TT, DM, FFD, FFD, slot, counts);
      k_gmm2<64, 64, MODE_B, EPI_DOWN, 2, 12, 2, 0><<<16 * 96, 256, 0, stream>>>(
          Hh, Hl, dw + (size_t)l * NE * FFD * DM, nullptr, nullptr,
          (long long)FFD * DM, nullptr, nullptr, eo, TT, FFD, DM, DM, nullptr, counts);
      k_combine_norm<0><<<TT, 256, 0, stream>>>(eo, topi, topw, posb, counts,
                                                x, n1w + (size_t)(l + 1) * DM, xh, xl);
    } else {
      k_gmm2<64, 128, MODE_GU, EPI_GU, 1, 32, 1, 0><<<16 * 256, 256, 0, stream>>>(
          xh, nullptr, gw + (size_t)l * NE * DM * FFD, uw + (size_t)l * NE * DM * FFD, nullptr,
          (long long)DM * FFD, Hh, nullptr, nullptr, TT, DM, FFD, FFD, slot, counts);
      k_gmm2<64, 64, MODE_B, EPI_DOWN, 2, 12, 1, 0><<<16 * 96, 256, 0, stream>>>(
          Hh, nullptr, dw + (size_t)l * NE * FFD * DM, nullptr, nullptr,
          (long long)FFD * DM, nullptr, nullptr, eo, TT, FFD, DM, DM, nullptr, counts);
      k_combine_norm<1><<<TT, 256, 0, stream>>>(eo, topi, topw, posb, counts,
                                                x, fnw, xnb, nullptr);
    }
  }

  // LM head: single launch, XCD-grouped panel decode
  k_gmm2<64, 128, MODE_B, EPI_F32, 0, 250, 1, 2><<<16 * 256, 256, 0, stream>>>(
      xnb, nullptr, lmw, nullptr, nullptr,
      0, nullptr, nullptr, out, TT, DM, NV, NV, nullptr, nullptr);
}